// Round 8
// baseline (283.899 us; speedup 1.0000x reference)
//
#include <hip/hip_runtime.h>

#define N_NODES 100000
#define F1 128
#define NCLS 64
#define EPB 8   // edges per thread in CSR-build kernels

typedef __attribute__((ext_vector_type(8))) short bf16x8;
typedef __attribute__((ext_vector_type(4))) float f32x4;

__device__ __forceinline__ unsigned f2bf(float x) {
    unsigned u = __builtin_bit_cast(unsigned, x);
    u += 0x7fff + ((u >> 16) & 1);
    return u >> 16;
}
__device__ __forceinline__ float bflo(unsigned u) {
    return __builtin_bit_cast(float, u << 16);
}
__device__ __forceinline__ float bfhi(unsigned u) {
    return __builtin_bit_cast(float, u & 0xffff0000u);
}

// ds_swizzle helpers (offset BitMode: lane i reads ((i&and)|or)^xor, per 32-lane half)
#define SWZ_I(v, off) __builtin_amdgcn_ds_swizzle((v), (off))
#define SWZ_F(v, off) __builtin_bit_cast(float, __builtin_amdgcn_ds_swizzle(__builtin_bit_cast(int, (v)), (off)))

// ---------------------------------------------------------------------------
// Edge dtype probe (int64 vs int32 edge_index)
__global__ void detect_kernel(const int* __restrict__ ei, int* __restrict__ flag) {
    int tid = threadIdx.x;
    int v = ei[2 * tid + 1];
    unsigned long long ball = __ballot(v == 0);
    if (tid == 0) *flag = (ball == ~0ull) ? 1 : 0;
}

__device__ __forceinline__ int load_edge(const int* ei, int is64, long long idx) {
    return is64 ? ei[2 * idx] : ei[idx];
}

// ---------------------------------------------------------------------------
// FUSED kernel: blocks [0, nG1) do layer1 MFMA GEMM; blocks [nG1, nG1+nCB)
// do XCD-sharded degree counting (shard = count-block-id & 7; under
// round-robin dispatch each shard's cnt plane stays in one XCD's L2).
__global__ __launch_bounds__(256) void countgemm_kernel(
        const int* __restrict__ ei, const int* __restrict__ flag,
        int* __restrict__ cnt8, int* __restrict__ rank, int E, int nG1,
        const float* __restrict__ x, const float* __restrict__ W,
        const float* __restrict__ att_s, const float* __restrict__ att_d,
        unsigned* __restrict__ hp, float* __restrict__ as_, float* __restrict__ ad_, int n) {
    __shared__ uint4 WtS[2048];                 // 32 KB: Wt[128ch][128k] bf16
    int tid = threadIdx.x;
    if (blockIdx.x >= (unsigned)nG1) {
        // ---------------- count part ----------------
        int cbid = blockIdx.x - nG1;
        long long base = ((long long)cbid * 256 + tid) * EPB;
        if (base >= E) return;
        int* cnt = cnt8 + (size_t)(cbid & 7) * n;
        int is64 = *flag;
        int d[EPB];
        #pragma unroll
        for (int k = 0; k < EPB; ++k) {
            long long e = base + k;
            d[k] = (e < E) ? load_edge(ei, is64, (long long)E + e) : -1;
        }
        int r[EPB];
        #pragma unroll
        for (int k = 0; k < EPB; ++k)
            if (d[k] >= 0) r[k] = atomicAdd(&cnt[d[k]], 1);
        #pragma unroll
        for (int k = 0; k < EPB; ++k)
            if (d[k] >= 0) rank[base + k] = r[k];
        return;
    }
    // ---------------- gemm1 part ----------------
    unsigned* Wt = (unsigned*)WtS;
    {   // stage W^T (convert f32->bf16), swizzle bytecol ^= (ch&7)<<4
        int ch = tid & 127, fb = tid >> 7;
        #pragma unroll
        for (int j8 = 0; j8 < 8; ++j8) {
            int f0 = fb * 64 + j8 * 8;
            unsigned pk[4];
            #pragma unroll
            for (int p = 0; p < 4; ++p) {
                float lo = W[(size_t)(f0 + 2 * p) * 128 + ch];
                float hi = W[(size_t)(f0 + 2 * p + 1) * 128 + ch];
                pk[p] = f2bf(lo) | (f2bf(hi) << 16);
            }
            int bcol = (f0 * 2) ^ ((ch & 7) << 4);
            *(uint4*)&Wt[ch * 64 + (bcol >> 2)] = *(uint4*)pk;
        }
    }
    __syncthreads();
    int lane = tid & 63, w = tid >> 6;
    int col = lane & 15, quad = lane >> 4;
    int nodebase = blockIdx.x * 128 + w * 32;
    bf16x8 a[2][4];
    #pragma unroll
    for (int s = 0; s < 2; ++s) {
        int node = nodebase + s * 16 + col;
        const float* xr = x + (size_t)node * 128;
        bool v = node < n;
        #pragma unroll
        for (int kk = 0; kk < 4; ++kk) {
            float4 lo = v ? *(const float4*)&xr[kk * 32 + quad * 8]
                          : make_float4(0.f, 0.f, 0.f, 0.f);
            float4 hi = v ? *(const float4*)&xr[kk * 32 + quad * 8 + 4]
                          : make_float4(0.f, 0.f, 0.f, 0.f);
            unsigned pk[4];
            pk[0] = f2bf(lo.x) | (f2bf(lo.y) << 16);
            pk[1] = f2bf(lo.z) | (f2bf(lo.w) << 16);
            pk[2] = f2bf(hi.x) | (f2bf(hi.y) << 16);
            pk[3] = f2bf(hi.z) | (f2bf(hi.w) << 16);
            a[s][kk] = *(bf16x8*)pk;
        }
    }
    f32x4 acc[2][8] = {};
    #pragma unroll
    for (int c = 0; c < 8; ++c) {
        int brow = c * 16 + col;
        bf16x8 b[4];
        #pragma unroll
        for (int kk = 0; kk < 4; ++kk) {
            int bcol = (kk * 64 + quad * 16) ^ ((brow & 7) << 4);
            b[kk] = *(bf16x8*)&Wt[brow * 64 + (bcol >> 2)];
        }
        #pragma unroll
        for (int s = 0; s < 2; ++s)
            #pragma unroll
            for (int kk = 0; kk < 4; ++kk)
                acc[s][c] = __builtin_amdgcn_mfma_f32_16x16x32_bf16(a[s][kk], b[kk], acc[s][c], 0, 0, 0);
    }
    float aS[8], aD[8];
    #pragma unroll
    for (int c = 0; c < 8; ++c) { aS[c] = att_s[c * 16 + col]; aD[c] = att_d[c * 16 + col]; }
    #pragma unroll
    for (int s = 0; s < 2; ++s) {
        #pragma unroll
        for (int c = 0; c < 8; ++c) {
            #pragma unroll
            for (int r = 0; r < 4; ++r) {
                float own = acc[s][c][r];
                float par = SWZ_F(own, 0x041F);        // lane ^ 1
                int node = nodebase + s * 16 + quad * 4 + r;
                if (!(lane & 1) && node < n)
                    hp[(size_t)node * 64 + c * 8 + (col >> 1)] =
                        f2bf(own) | (f2bf(par) << 16);
            }
        }
        #pragma unroll
        for (int h = 0; h < 4; ++h) {
            #pragma unroll
            for (int r = 0; r < 4; ++r) {
                float ps = acc[s][2 * h][r] * aS[2 * h] + acc[s][2 * h + 1][r] * aS[2 * h + 1];
                float pd = acc[s][2 * h][r] * aD[2 * h] + acc[s][2 * h + 1][r] * aD[2 * h + 1];
                ps += SWZ_F(ps, 0x041F); pd += SWZ_F(pd, 0x041F);
                ps += SWZ_F(ps, 0x081F); pd += SWZ_F(pd, 0x081F);
                ps += SWZ_F(ps, 0x101F); pd += SWZ_F(pd, 0x101F);
                ps += SWZ_F(ps, 0x201F); pd += SWZ_F(pd, 0x201F);
                int node = nodebase + s * 16 + quad * 4 + r;
                if (col == 0 && node < n) {
                    as_[(size_t)node * 4 + h] = ps;
                    ad_[(size_t)node * 4 + h] = pd;
                }
            }
        }
    }
}

#define SCAN_BLOCK 1024
// scanA: per node, sum 8 shard counts -> total; write per-shard exclusive
// prefix IN PLACE into cnt8; block-scan totals into row_ptr(excl)+bsum.
__global__ void scanA_kernel(int* __restrict__ cnt8, int* __restrict__ excl,
                             int* __restrict__ bsum, int n) {
    __shared__ int sm[SCAN_BLOCK];
    int tid = threadIdx.x;
    int i = blockIdx.x * SCAN_BLOCK + tid;
    int tot = 0;
    if (i < n) {
        int p = 0;
        #pragma unroll
        for (int s = 0; s < 8; ++s) {
            int c = cnt8[(size_t)s * n + i];
            cnt8[(size_t)s * n + i] = p;
            p += c;
        }
        tot = p;
    }
    sm[tid] = tot;
    __syncthreads();
    for (int off = 1; off < SCAN_BLOCK; off <<= 1) {
        int t = (tid >= off) ? sm[tid - off] : 0;
        __syncthreads();
        sm[tid] += t;
        __syncthreads();
    }
    if (i < n) excl[i] = sm[tid] - tot;
    if (tid == SCAN_BLOCK - 1) bsum[blockIdx.x] = sm[tid];
}

__global__ void scanB_kernel(int* __restrict__ bsum, int nb,
                             int* __restrict__ row_last, int total) {
    __shared__ int sm[128];
    int tid = threadIdx.x;
    int v = (tid < nb) ? bsum[tid] : 0;
    sm[tid] = v;
    __syncthreads();
    for (int off = 1; off < 128; off <<= 1) {
        int t = (tid >= off) ? sm[tid - off] : 0;
        __syncthreads();
        sm[tid] += t;
        __syncthreads();
    }
    if (tid < nb) bsum[tid] = sm[tid] - v;
    if (tid == 0) *row_last = total;
}

// scanC: finalize row_ptr and fold it into every shard plane (cnt8 becomes
// the absolute fill base per (shard, node)).
__global__ void scanC_kernel(int* __restrict__ row_ptr, int* __restrict__ cnt8,
                             const int* __restrict__ bsum, int n) {
    int i = blockIdx.x * SCAN_BLOCK + threadIdx.x;
    if (i < n) {
        int rp = row_ptr[i] + bsum[blockIdx.x];
        row_ptr[i] = rp;
        #pragma unroll
        for (int s = 0; s < 8; ++s) cnt8[(size_t)s * n + i] += rp;
    }
}

__global__ void fill_kernel(const int* __restrict__ ei, const int* __restrict__ flag,
                            const int* __restrict__ cnt8, const int* __restrict__ rank,
                            int* __restrict__ col, int E, int n) {
    long long base = ((long long)blockIdx.x * 256 + threadIdx.x) * EPB;
    if (base >= E) return;
    const int* sbase = cnt8 + (size_t)(blockIdx.x & 7) * n;
    int is64 = *flag;
    int d[EPB], s[EPB], r[EPB], rp[EPB];
    #pragma unroll
    for (int k = 0; k < EPB; ++k) {
        long long e = base + k;
        d[k] = (e < E) ? load_edge(ei, is64, (long long)E + e) : -1;
    }
    #pragma unroll
    for (int k = 0; k < EPB; ++k) {
        long long e = base + k;
        s[k] = (e < E) ? load_edge(ei, is64, e) : 0;
    }
    #pragma unroll
    for (int k = 0; k < EPB; ++k)
        if (d[k] >= 0) { r[k] = rank[base + k]; }
    #pragma unroll
    for (int k = 0; k < EPB; ++k)
        if (d[k] >= 0) rp[k] = sbase[d[k]];
    #pragma unroll
    for (int k = 0; k < EPB; ++k)
        if (d[k] >= 0) col[rp[k] + r[k]] = s[k];
}

// ---------------------------------------------------------------------------
// Layer2 GEMM via MFMA bf16: [N,128(bf16-packed)]x[128,64].
__global__ __launch_bounds__(256) void gemm2_kernel(
        const unsigned* __restrict__ xp, const float* __restrict__ W,
        const float* __restrict__ att_s, const float* __restrict__ att_d,
        unsigned* __restrict__ hp, float* __restrict__ as_, float* __restrict__ ad_, int n) {
    __shared__ uint4 WtS[1024];                 // 16 KB: Wt[64ch][128k] bf16
    unsigned* Wt = (unsigned*)WtS;
    int tid = threadIdx.x;
    {   // stage W2^T
        int ch = tid & 63, fb = tid >> 6;
        #pragma unroll
        for (int j8 = 0; j8 < 4; ++j8) {
            int f0 = fb * 32 + j8 * 8;
            unsigned pk[4];
            #pragma unroll
            for (int p = 0; p < 4; ++p) {
                float lo = W[(size_t)(f0 + 2 * p) * 64 + ch];
                float hi = W[(size_t)(f0 + 2 * p + 1) * 64 + ch];
                pk[p] = f2bf(lo) | (f2bf(hi) << 16);
            }
            int bcol = (f0 * 2) ^ ((ch & 7) << 4);
            *(uint4*)&Wt[ch * 64 + (bcol >> 2)] = *(uint4*)pk;
        }
    }
    __syncthreads();
    int lane = tid & 63, w = tid >> 6;
    int col = lane & 15, quad = lane >> 4;
    int nodebase = blockIdx.x * 128 + w * 32;
    bf16x8 a[2][4];
    #pragma unroll
    for (int s = 0; s < 2; ++s) {
        int node = nodebase + s * 16 + col;
        bool v = node < n;
        #pragma unroll
        for (int kk = 0; kk < 4; ++kk) {
            uint4 u = v ? *(const uint4*)&xp[(size_t)node * 64 + kk * 16 + quad * 4]
                        : make_uint4(0, 0, 0, 0);
            a[s][kk] = *(bf16x8*)&u;
        }
    }
    f32x4 acc[2][4] = {};
    #pragma unroll
    for (int c = 0; c < 4; ++c) {
        int brow = c * 16 + col;
        bf16x8 b[4];
        #pragma unroll
        for (int kk = 0; kk < 4; ++kk) {
            int bcol = (kk * 64 + quad * 16) ^ ((brow & 7) << 4);
            b[kk] = *(bf16x8*)&Wt[brow * 64 + (bcol >> 2)];
        }
        #pragma unroll
        for (int s = 0; s < 2; ++s)
            #pragma unroll
            for (int kk = 0; kk < 4; ++kk)
                acc[s][c] = __builtin_amdgcn_mfma_f32_16x16x32_bf16(a[s][kk], b[kk], acc[s][c], 0, 0, 0);
    }
    float aS[4], aD[4];
    #pragma unroll
    for (int c = 0; c < 4; ++c) { aS[c] = att_s[c * 16 + col]; aD[c] = att_d[c * 16 + col]; }
    #pragma unroll
    for (int s = 0; s < 2; ++s) {
        #pragma unroll
        for (int c = 0; c < 4; ++c) {
            #pragma unroll
            for (int r = 0; r < 4; ++r) {
                float own = acc[s][c][r];
                float par = SWZ_F(own, 0x041F);
                int node = nodebase + s * 16 + quad * 4 + r;
                if (!(lane & 1) && node < n)
                    hp[(size_t)node * 32 + c * 8 + (col >> 1)] =
                        f2bf(own) | (f2bf(par) << 16);
            }
        }
        #pragma unroll
        for (int r = 0; r < 4; ++r) {
            float ps = 0.f, pd = 0.f;
            #pragma unroll
            for (int c = 0; c < 4; ++c) {
                ps = fmaf(acc[s][c][r], aS[c], ps);
                pd = fmaf(acc[s][c][r], aD[c], pd);
            }
            ps += SWZ_F(ps, 0x041F); pd += SWZ_F(pd, 0x041F);
            ps += SWZ_F(ps, 0x081F); pd += SWZ_F(pd, 0x081F);
            ps += SWZ_F(ps, 0x101F); pd += SWZ_F(pd, 0x101F);
            ps += SWZ_F(ps, 0x201F); pd += SWZ_F(pd, 0x201F);
            int node = nodebase + s * 16 + quad * 4 + r;
            if (col == 0 && node < n) { as_[node] = ps; ad_[node] = pd; }
        }
    }
}

// ---------------------------------------------------------------------------
// Aggregation layer1: wave per dst node, lane owns channels (2l, 2l+1),
// head = lane>>4. 32-edge chunks mirrored into both 32-lane halves; weights
// computed once per (edge, head) in lane layout (edge&15 | head<<4) and
// broadcast via single-instruction ds_swizzle. Branch-free 8-edge groups.
#define A1_G8(B, K0) { \
    int t0 = SWZ_I(myc, (((B)+(K0)+0)<<5)); \
    int t1 = SWZ_I(myc, (((B)+(K0)+1)<<5)); \
    int t2 = SWZ_I(myc, (((B)+(K0)+2)<<5)); \
    int t3 = SWZ_I(myc, (((B)+(K0)+3)<<5)); \
    int t4 = SWZ_I(myc, (((B)+(K0)+4)<<5)); \
    int t5 = SWZ_I(myc, (((B)+(K0)+5)<<5)); \
    int t6 = SWZ_I(myc, (((B)+(K0)+6)<<5)); \
    int t7 = SWZ_I(myc, (((B)+(K0)+7)<<5)); \
    unsigned v0 = hp[(size_t)t0 * 64 + lane]; \
    unsigned v1 = hp[(size_t)t1 * 64 + lane]; \
    unsigned v2 = hp[(size_t)t2 * 64 + lane]; \
    unsigned v3 = hp[(size_t)t3 * 64 + lane]; \
    unsigned v4 = hp[(size_t)t4 * 64 + lane]; \
    unsigned v5 = hp[(size_t)t5 * 64 + lane]; \
    unsigned v6 = hp[(size_t)t6 * 64 + lane]; \
    unsigned v7 = hp[(size_t)t7 * 64 + lane]; \
    float q0 = SWZ_F(ew, ((((K0)+0)<<5)|0x10)); \
    float q1 = SWZ_F(ew, ((((K0)+1)<<5)|0x10)); \
    float q2 = SWZ_F(ew, ((((K0)+2)<<5)|0x10)); \
    float q3 = SWZ_F(ew, ((((K0)+3)<<5)|0x10)); \
    float q4 = SWZ_F(ew, ((((K0)+4)<<5)|0x10)); \
    float q5 = SWZ_F(ew, ((((K0)+5)<<5)|0x10)); \
    float q6 = SWZ_F(ew, ((((K0)+6)<<5)|0x10)); \
    float q7 = SWZ_F(ew, ((((K0)+7)<<5)|0x10)); \
    s += q0; acc0 = fmaf(q0, bflo(v0), acc0); acc1 = fmaf(q0, bfhi(v0), acc1); \
    s += q1; acc0 = fmaf(q1, bflo(v1), acc0); acc1 = fmaf(q1, bfhi(v1), acc1); \
    s += q2; acc0 = fmaf(q2, bflo(v2), acc0); acc1 = fmaf(q2, bfhi(v2), acc1); \
    s += q3; acc0 = fmaf(q3, bflo(v3), acc0); acc1 = fmaf(q3, bfhi(v3), acc1); \
    s += q4; acc0 = fmaf(q4, bflo(v4), acc0); acc1 = fmaf(q4, bfhi(v4), acc1); \
    s += q5; acc0 = fmaf(q5, bflo(v5), acc0); acc1 = fmaf(q5, bfhi(v5), acc1); \
    s += q6; acc0 = fmaf(q6, bflo(v6), acc0); acc1 = fmaf(q6, bfhi(v6), acc1); \
    s += q7; acc0 = fmaf(q7, bflo(v7), acc0); acc1 = fmaf(q7, bfhi(v7), acc1); }

#define A1_SUB(B) { \
    int sspec = SWZ_I(myc, (((B)<<5) | 0x0F)); \
    float ee_ = as_[(size_t)sspec * 4 + head] + adv; \
    ee_ = fmaxf(ee_, 0.2f * ee_); \
    float ew = ((cb + (B) + (lane & 15)) < end) ? __expf(ee_) : 0.f; \
    A1_G8(B, 0) \
    if (m > (B) + 8) A1_G8(B, 8) }

__global__ __launch_bounds__(256) void agg1_kernel(
        const unsigned* __restrict__ hp, const float* __restrict__ as_,
        const float* __restrict__ ad_, const int* __restrict__ row_ptr,
        const int* __restrict__ col, const float* __restrict__ bias,
        unsigned* __restrict__ outp, int n) {
    int wid = (blockIdx.x * 256 + threadIdx.x) >> 6;
    int lane = threadIdx.x & 63;
    if (wid >= n) return;
    int node = wid;
    int head = lane >> 4;                   // head of channels (2l, 2l+1)
    float adv = ad_[(size_t)node * 4 + head];
    float e0 = as_[(size_t)node * 4 + head] + adv;
    e0 = fmaxf(e0, 0.2f * e0);
    float w0 = __expf(e0);
    float s = w0;
    unsigned u0 = hp[(size_t)node * 64 + lane];
    float acc0 = w0 * bflo(u0), acc1 = w0 * bfhi(u0);
    int beg = row_ptr[node], end = row_ptr[node + 1];
    for (int cb = beg; cb < end; cb += 32) {
        int m = end - cb; if (m > 32) m = 32;
        int ci = cb + (lane & 31);
        int myc = col[(ci < end) ? ci : (end - 1)];   // mirrored into both halves
        A1_SUB(0)
        if (m > 16) A1_SUB(16)
    }
    float inv = 1.0f / (s + 1e-16f);
    float2 b = *(const float2*)&bias[lane * 2];
    outp[(size_t)node * 64 + lane] =
        f2bf(acc0 * inv + b.x) | (f2bf(acc1 * inv + b.y) << 16);
}

// Aggregation layer2: wave per dst node; halves process even/odd edges.
#define A2_G4(K0) { \
    int t0 = SWZ_I(myc, (((K0)+0)<<5)); \
    int t1 = SWZ_I(myc, (((K0)+1)<<5)); \
    int t2 = SWZ_I(myc, (((K0)+2)<<5)); \
    int t3 = SWZ_I(myc, (((K0)+3)<<5)); \
    unsigned v0 = hp[(size_t)t0 * 32 + wrd]; \
    unsigned v1 = hp[(size_t)t1 * 32 + wrd]; \
    unsigned v2 = hp[(size_t)t2 * 32 + wrd]; \
    unsigned v3 = hp[(size_t)t3 * 32 + wrd]; \
    float q0 = SWZ_F(ew, (((K0)+0)<<5)); \
    float q1 = SWZ_F(ew, (((K0)+1)<<5)); \
    float q2 = SWZ_F(ew, (((K0)+2)<<5)); \
    float q3 = SWZ_F(ew, (((K0)+3)<<5)); \
    s += q0; acc0 = fmaf(q0, bflo(v0), acc0); acc1 = fmaf(q0, bfhi(v0), acc1); \
    s += q1; acc0 = fmaf(q1, bflo(v1), acc0); acc1 = fmaf(q1, bfhi(v1), acc1); \
    s += q2; acc0 = fmaf(q2, bflo(v2), acc0); acc1 = fmaf(q2, bfhi(v2), acc1); \
    s += q3; acc0 = fmaf(q3, bflo(v3), acc0); acc1 = fmaf(q3, bfhi(v3), acc1); }

__global__ __launch_bounds__(256) void agg2_kernel(
        const unsigned* __restrict__ hp, const float* __restrict__ as_,
        const float* __restrict__ ad_, const int* __restrict__ row_ptr,
        const int* __restrict__ col, const float* __restrict__ bias,
        float* __restrict__ out, int n) {
    int wid = (blockIdx.x * 256 + threadIdx.x) >> 6;
    int lane = threadIdx.x & 63;
    if (wid >= n) return;
    int node = wid;
    int half = lane >> 5, wrd = lane & 31;
    float adv = ad_[node];
    float s = 0.f, acc0 = 0.f, acc1 = 0.f;
    {
        float e = as_[node] + adv; e = fmaxf(e, 0.2f * e);
        float w = __expf(e);
        if (half == 0) {
            unsigned u = hp[(size_t)node * 32 + wrd];
            s = w; acc0 = w * bflo(u); acc1 = w * bfhi(u);
        }
    }
    int beg = row_ptr[node], end = row_ptr[node + 1];
    for (int cb = beg; cb < end; cb += 64) {
        int m = end - cb; if (m > 64) m = 64;
        int idx = cb + 2 * (lane & 31) + half;
        int myc = col[(idx < end) ? idx : (end - 1)];
        float ee = as_[myc] + adv; ee = fmaxf(ee, 0.2f * ee);
        float ew = (idx < end) ? __expf(ee) : 0.f;
        A2_G4(0)
        if (m > 8)  A2_G4(4)
        if (m > 16) A2_G4(8)
        if (m > 24) A2_G4(12)
        if (m > 32) {
            A2_G4(16)
            if (m > 40) A2_G4(20)
            if (m > 48) A2_G4(24)
            if (m > 56) A2_G4(28)
        }
    }
    s += __shfl_xor(s, 32);
    acc0 += __shfl_xor(acc0, 32);
    acc1 += __shfl_xor(acc1, 32);
    if (half == 0) {
        float inv = 1.0f / (s + 1e-16f);
        float2 b = *(const float2*)&bias[wrd * 2];
        *(float2*)&out[(size_t)node * 64 + wrd * 2] =
            make_float2(acc0 * inv + b.x, acc1 * inv + b.y);
    }
}

// ---------------------------------------------------------------------------
extern "C" void kernel_launch(void* const* d_in, const int* in_sizes, int n_in,
                              void* d_out, int out_size, void* d_ws, size_t ws_size,
                              hipStream_t stream) {
    const float* inp   = (const float*)d_in[0];
    const int*   ei    = (const int*)d_in[1];
    const float* W1    = (const float*)d_in[2];
    const float* atts1 = (const float*)d_in[3];
    const float* attd1 = (const float*)d_in[4];
    const float* bias1 = (const float*)d_in[5];
    const float* W2    = (const float*)d_in[6];
    const float* atts2 = (const float*)d_in[7];
    const float* attd2 = (const float*)d_in[8];
    const float* bias2 = (const float*)d_in[9];
    float* out = (float*)d_out;

    const int N = N_NODES;
    const int E = in_sizes[1] / 2;

    unsigned* h1p = (unsigned*)d_ws;               // N*64 uints (layer2 reuses N*32)
    unsigned* x1p = h1p + (size_t)N * 64;          // N*64 uints (bf16-packed x1)
    float* as1 = (float*)(x1p + (size_t)N * 64);   // N*4
    float* ad1 = as1 + (size_t)N * 4;              // N*4
    int* cnt8     = (int*)(ad1 + (size_t)N * 4);   // 8*N (count planes -> fill bases)
    int* row_ptr  = cnt8 + (size_t)8 * N;          // N+1
    int* bsum     = row_ptr + N + 1;               // 128
    int* flag     = bsum + 128;                    // 1
    int* col      = flag + 1;                      // E
    int* rank     = (int*)x1p;                     // E ints, aliases x1p (dead before agg1)

    hipMemsetAsync(cnt8, 0, (size_t)8 * N * sizeof(int), stream);
    detect_kernel<<<1, 64, 0, stream>>>(ei, flag);

    int nb = (N + SCAN_BLOCK - 1) / SCAN_BLOCK;
    int nCB = (E + 256 * EPB - 1) / (256 * EPB);   // count blocks
    int nG1 = (N + 127) / 128;                     // gemm1 blocks

    // fused: layer1 GEMM (blocks [0,nG1)) + sharded degree count (rest)
    countgemm_kernel<<<nG1 + nCB, 256, 0, stream>>>(
        ei, flag, cnt8, rank, E, nG1, inp, W1, atts1, attd1, h1p, as1, ad1, N);

    scanA_kernel<<<nb, SCAN_BLOCK, 0, stream>>>(cnt8, row_ptr, bsum, N);
    scanB_kernel<<<1, 128, 0, stream>>>(bsum, nb, row_ptr + N, E);
    scanC_kernel<<<nb, SCAN_BLOCK, 0, stream>>>(row_ptr, cnt8, bsum, N);
    fill_kernel<<<nCB, 256, 0, stream>>>(ei, flag, cnt8, rank, col, E, N);

    agg1_kernel<<<(N + 3) / 4, 256, 0, stream>>>(h1p, as1, ad1, row_ptr, col, bias1, x1p, N);

    // layer 2 (h2p aliases h1p; as2/ad2 alias as1/ad1)
    gemm2_kernel<<<(N + 127) / 128, 256, 0, stream>>>(x1p, W2, atts2, attd2, h1p, as1, ad1, N);
    agg2_kernel<<<(N + 3) / 4, 256, 0, stream>>>(h1p, as1, ad1, row_ptr, col, bias2, out, N);
}

// Round 9
// 220.835 us; speedup vs baseline: 1.2856x; 1.2856x over previous
//
#include <hip/hip_runtime.h>

#define N_NODES 100000
#define F1 128
#define NCLS 64
#define EPB 8   // edges per thread in edge-pass kernels

typedef __attribute__((ext_vector_type(8))) short bf16x8;
typedef __attribute__((ext_vector_type(4))) float f32x4;

__device__ __forceinline__ unsigned f2bf(float x) {
    unsigned u = __builtin_bit_cast(unsigned, x);
    u += 0x7fff + ((u >> 16) & 1);
    return u >> 16;
}
__device__ __forceinline__ float bflo(unsigned u) {
    return __builtin_bit_cast(float, u << 16);
}
__device__ __forceinline__ float bfhi(unsigned u) {
    return __builtin_bit_cast(float, u & 0xffff0000u);
}

// ds_swizzle helpers (offset BitMode: lane i reads ((i&and)|or)^xor, per 32-lane half)
#define SWZ_I(v, off) __builtin_amdgcn_ds_swizzle((v), (off))
#define SWZ_F(v, off) __builtin_bit_cast(float, __builtin_amdgcn_ds_swizzle(__builtin_bit_cast(int, (v)), (off)))

// ---------------------------------------------------------------------------
// Edge dtype probe (int64 vs int32 edge_index)
__global__ void detect_kernel(const int* __restrict__ ei, int* __restrict__ flag) {
    int tid = threadIdx.x;
    int v = ei[2 * tid + 1];
    unsigned long long ball = __ballot(v == 0);
    if (tid == 0) *flag = (ball == ~0ull) ? 1 : 0;
}

__device__ __forceinline__ int load_edge(const int* ei, int is64, long long idx) {
    return is64 ? ei[2 * idx] : ei[idx];
}

// ---------------------------------------------------------------------------
// Atomic-free CSR build: bucket = dst>>9 (256 buckets of 512 nodes).
// histA: per-block LDS histogram over buckets -> ghBM[bk*EB + blk].
__global__ __launch_bounds__(256) void histA_kernel(
        const int* __restrict__ ei, const int* __restrict__ flag,
        int* __restrict__ ghBM, int EB, int E) {
    __shared__ int bins[256];
    int tid = threadIdx.x;
    bins[tid] = 0;
    __syncthreads();
    long long base = (long long)blockIdx.x * 2048 + tid * EPB;
    int is64 = *flag;
    int d[EPB];
    #pragma unroll
    for (int k = 0; k < EPB; ++k) {
        long long e = base + k;
        d[k] = (e < E) ? load_edge(ei, is64, (long long)E + e) : -1;
    }
    #pragma unroll
    for (int k = 0; k < EPB; ++k)
        if (d[k] >= 0) atomicAdd(&bins[d[k] >> 9], 1);
    __syncthreads();
    ghBM[(size_t)tid * EB + blockIdx.x] = bins[tid];
}

// pscanA/B/C: exclusive scan over ghBM (length K = 256*EB), in place.
#define SCAN_BLOCK 1024
__global__ void pscanA_kernel(int* __restrict__ g, int* __restrict__ bsum, int K) {
    __shared__ int sm[SCAN_BLOCK];
    int tid = threadIdx.x;
    int i = blockIdx.x * SCAN_BLOCK + tid;
    int v = (i < K) ? g[i] : 0;
    sm[tid] = v;
    __syncthreads();
    for (int off = 1; off < SCAN_BLOCK; off <<= 1) {
        int t = (tid >= off) ? sm[tid - off] : 0;
        __syncthreads();
        sm[tid] += t;
        __syncthreads();
    }
    if (i < K) g[i] = sm[tid] - v;
    if (tid == SCAN_BLOCK - 1) bsum[blockIdx.x] = sm[tid];
}

__global__ void pscanB_kernel(int* __restrict__ bsum, int nb) {
    __shared__ int sm[256];
    int tid = threadIdx.x;
    int v = (tid < nb) ? bsum[tid] : 0;
    sm[tid] = v;
    __syncthreads();
    for (int off = 1; off < 256; off <<= 1) {
        int t = (tid >= off) ? sm[tid - off] : 0;
        __syncthreads();
        sm[tid] += t;
        __syncthreads();
    }
    if (tid < nb) bsum[tid] = sm[tid] - v;
}

__global__ void pscanC_kernel(int* __restrict__ g, const int* __restrict__ bsum, int K) {
    int i = blockIdx.x * SCAN_BLOCK + threadIdx.x;
    if (i < K) g[i] += bsum[blockIdx.x];
}

// scatterB: re-read edges, LDS-rank within (block, bucket), write packed
// (src | local<<17) into the bucket-partitioned tmp array. No global atomics.
__global__ __launch_bounds__(256) void scatterB_kernel(
        const int* __restrict__ ei, const int* __restrict__ flag,
        const int* __restrict__ ghBM, int EB,
        unsigned* __restrict__ tmp, int E) {
    __shared__ int base[256];
    int tid = threadIdx.x;
    base[tid] = ghBM[(size_t)tid * EB + blockIdx.x];
    __syncthreads();
    long long eb = (long long)blockIdx.x * 2048 + tid * EPB;
    int is64 = *flag;
    int d[EPB], s[EPB];
    #pragma unroll
    for (int k = 0; k < EPB; ++k) {
        long long e = eb + k;
        d[k] = (e < E) ? load_edge(ei, is64, (long long)E + e) : -1;
    }
    #pragma unroll
    for (int k = 0; k < EPB; ++k) {
        long long e = eb + k;
        s[k] = (e < E) ? load_edge(ei, is64, e) : 0;
    }
    #pragma unroll
    for (int k = 0; k < EPB; ++k) {
        if (d[k] >= 0) {
            int pos = atomicAdd(&base[d[k] >> 9], 1);
            tmp[pos] = (unsigned)s[k] | ((unsigned)(d[k] & 511) << 17);
        }
    }
}

// bucketC: one block per bucket. LDS count over 512 local nodes -> LDS scan
// -> row_ptr (global CSR offsets) + rank-scatter col.
__global__ __launch_bounds__(256) void bucketC_kernel(
        const unsigned* __restrict__ tmp, const int* __restrict__ ghBM, int EB,
        int* __restrict__ row_ptr, int* __restrict__ col, int E, int n) {
    __shared__ int lb[512];
    __shared__ int lo[512];
    __shared__ int sm[256];
    int bk = blockIdx.x;
    int tid = threadIdx.x;
    int gbase = ghBM[(size_t)bk * EB];
    int gend = (bk == 255) ? E : ghBM[(size_t)(bk + 1) * EB];
    int cnt = gend - gbase;
    lb[tid] = 0; lb[tid + 256] = 0;
    __syncthreads();
    for (int i = tid; i < cnt; i += 256)
        atomicAdd(&lb[tmp[gbase + i] >> 17], 1);
    __syncthreads();
    // exclusive scan over 512 bins (pair-sum + 256-wide Hillis-Steele)
    int p = lb[2 * tid], q = lb[2 * tid + 1];
    int ps = p + q;
    sm[tid] = ps;
    __syncthreads();
    for (int off = 1; off < 256; off <<= 1) {
        int t = (tid >= off) ? sm[tid - off] : 0;
        __syncthreads();
        sm[tid] += t;
        __syncthreads();
    }
    int excl = sm[tid] - ps;
    int e0 = excl, e1 = excl + p;
    lo[2 * tid] = e0; lo[2 * tid + 1] = e1;
    int v0 = bk * 512 + 2 * tid;
    if (v0 <= n) row_ptr[v0] = gbase + e0;
    if (v0 + 1 <= n) row_ptr[v0 + 1] = gbase + e1;
    __syncthreads();
    for (int i = tid; i < cnt; i += 256) {
        unsigned v = tmp[gbase + i];
        int r = atomicAdd(&lo[v >> 17], 1);
        col[gbase + r] = (int)(v & 0x1FFFFu);
    }
}

// ---------------------------------------------------------------------------
// Layer1 GEMM via MFMA bf16: h = x @ W1, [N,128]x[128,128].
__global__ __launch_bounds__(256) void gemm1_kernel(
        const float* __restrict__ x, const float* __restrict__ W,
        const float* __restrict__ att_s, const float* __restrict__ att_d,
        unsigned* __restrict__ hp, float* __restrict__ as_, float* __restrict__ ad_, int n) {
    __shared__ uint4 WtS[2048];                 // 32 KB: Wt[128ch][128k] bf16
    unsigned* Wt = (unsigned*)WtS;
    int tid = threadIdx.x;
    {   // stage W^T (convert f32->bf16), swizzle bytecol ^= (ch&7)<<4
        int ch = tid & 127, fb = tid >> 7;
        #pragma unroll
        for (int j8 = 0; j8 < 8; ++j8) {
            int f0 = fb * 64 + j8 * 8;
            unsigned pk[4];
            #pragma unroll
            for (int p = 0; p < 4; ++p) {
                float lo = W[(size_t)(f0 + 2 * p) * 128 + ch];
                float hi = W[(size_t)(f0 + 2 * p + 1) * 128 + ch];
                pk[p] = f2bf(lo) | (f2bf(hi) << 16);
            }
            int bcol = (f0 * 2) ^ ((ch & 7) << 4);
            *(uint4*)&Wt[ch * 64 + (bcol >> 2)] = *(uint4*)pk;
        }
    }
    __syncthreads();
    int lane = tid & 63, w = tid >> 6;
    int col = lane & 15, quad = lane >> 4;
    int nodebase = blockIdx.x * 128 + w * 32;
    bf16x8 a[2][4];
    #pragma unroll
    for (int s = 0; s < 2; ++s) {
        int node = nodebase + s * 16 + col;
        const float* xr = x + (size_t)node * 128;
        bool v = node < n;
        #pragma unroll
        for (int kk = 0; kk < 4; ++kk) {
            float4 lo = v ? *(const float4*)&xr[kk * 32 + quad * 8]
                          : make_float4(0.f, 0.f, 0.f, 0.f);
            float4 hi = v ? *(const float4*)&xr[kk * 32 + quad * 8 + 4]
                          : make_float4(0.f, 0.f, 0.f, 0.f);
            unsigned pk[4];
            pk[0] = f2bf(lo.x) | (f2bf(lo.y) << 16);
            pk[1] = f2bf(lo.z) | (f2bf(lo.w) << 16);
            pk[2] = f2bf(hi.x) | (f2bf(hi.y) << 16);
            pk[3] = f2bf(hi.z) | (f2bf(hi.w) << 16);
            a[s][kk] = *(bf16x8*)pk;
        }
    }
    f32x4 acc[2][8] = {};
    #pragma unroll
    for (int c = 0; c < 8; ++c) {
        int brow = c * 16 + col;
        bf16x8 b[4];
        #pragma unroll
        for (int kk = 0; kk < 4; ++kk) {
            int bcol = (kk * 64 + quad * 16) ^ ((brow & 7) << 4);
            b[kk] = *(bf16x8*)&Wt[brow * 64 + (bcol >> 2)];
        }
        #pragma unroll
        for (int s = 0; s < 2; ++s)
            #pragma unroll
            for (int kk = 0; kk < 4; ++kk)
                acc[s][c] = __builtin_amdgcn_mfma_f32_16x16x32_bf16(a[s][kk], b[kk], acc[s][c], 0, 0, 0);
    }
    float aS[8], aD[8];
    #pragma unroll
    for (int c = 0; c < 8; ++c) { aS[c] = att_s[c * 16 + col]; aD[c] = att_d[c * 16 + col]; }
    #pragma unroll
    for (int s = 0; s < 2; ++s) {
        #pragma unroll
        for (int c = 0; c < 8; ++c) {
            #pragma unroll
            for (int r = 0; r < 4; ++r) {
                float own = acc[s][c][r];
                float par = SWZ_F(own, 0x041F);        // lane ^ 1
                int node = nodebase + s * 16 + quad * 4 + r;
                if (!(lane & 1) && node < n)
                    hp[(size_t)node * 64 + c * 8 + (col >> 1)] =
                        f2bf(own) | (f2bf(par) << 16);
            }
        }
        #pragma unroll
        for (int h = 0; h < 4; ++h) {
            #pragma unroll
            for (int r = 0; r < 4; ++r) {
                float ps = acc[s][2 * h][r] * aS[2 * h] + acc[s][2 * h + 1][r] * aS[2 * h + 1];
                float pd = acc[s][2 * h][r] * aD[2 * h] + acc[s][2 * h + 1][r] * aD[2 * h + 1];
                ps += SWZ_F(ps, 0x041F); pd += SWZ_F(pd, 0x041F);
                ps += SWZ_F(ps, 0x081F); pd += SWZ_F(pd, 0x081F);
                ps += SWZ_F(ps, 0x101F); pd += SWZ_F(pd, 0x101F);
                ps += SWZ_F(ps, 0x201F); pd += SWZ_F(pd, 0x201F);
                int node = nodebase + s * 16 + quad * 4 + r;
                if (col == 0 && node < n) {
                    as_[(size_t)node * 4 + h] = ps;
                    ad_[(size_t)node * 4 + h] = pd;
                }
            }
        }
    }
}

// Layer2 GEMM via MFMA bf16: [N,128(bf16-packed)]x[128,64].
__global__ __launch_bounds__(256) void gemm2_kernel(
        const unsigned* __restrict__ xp, const float* __restrict__ W,
        const float* __restrict__ att_s, const float* __restrict__ att_d,
        unsigned* __restrict__ hp, float* __restrict__ as_, float* __restrict__ ad_, int n) {
    __shared__ uint4 WtS[1024];                 // 16 KB: Wt[64ch][128k] bf16
    unsigned* Wt = (unsigned*)WtS;
    int tid = threadIdx.x;
    {   // stage W2^T
        int ch = tid & 63, fb = tid >> 6;
        #pragma unroll
        for (int j8 = 0; j8 < 4; ++j8) {
            int f0 = fb * 32 + j8 * 8;
            unsigned pk[4];
            #pragma unroll
            for (int p = 0; p < 4; ++p) {
                float lo = W[(size_t)(f0 + 2 * p) * 64 + ch];
                float hi = W[(size_t)(f0 + 2 * p + 1) * 64 + ch];
                pk[p] = f2bf(lo) | (f2bf(hi) << 16);
            }
            int bcol = (f0 * 2) ^ ((ch & 7) << 4);
            *(uint4*)&Wt[ch * 64 + (bcol >> 2)] = *(uint4*)pk;
        }
    }
    __syncthreads();
    int lane = tid & 63, w = tid >> 6;
    int col = lane & 15, quad = lane >> 4;
    int nodebase = blockIdx.x * 128 + w * 32;
    bf16x8 a[2][4];
    #pragma unroll
    for (int s = 0; s < 2; ++s) {
        int node = nodebase + s * 16 + col;
        bool v = node < n;
        #pragma unroll
        for (int kk = 0; kk < 4; ++kk) {
            uint4 u = v ? *(const uint4*)&xp[(size_t)node * 64 + kk * 16 + quad * 4]
                        : make_uint4(0, 0, 0, 0);
            a[s][kk] = *(bf16x8*)&u;
        }
    }
    f32x4 acc[2][4] = {};
    #pragma unroll
    for (int c = 0; c < 4; ++c) {
        int brow = c * 16 + col;
        bf16x8 b[4];
        #pragma unroll
        for (int kk = 0; kk < 4; ++kk) {
            int bcol = (kk * 64 + quad * 16) ^ ((brow & 7) << 4);
            b[kk] = *(bf16x8*)&Wt[brow * 64 + (bcol >> 2)];
        }
        #pragma unroll
        for (int s = 0; s < 2; ++s)
            #pragma unroll
            for (int kk = 0; kk < 4; ++kk)
                acc[s][c] = __builtin_amdgcn_mfma_f32_16x16x32_bf16(a[s][kk], b[kk], acc[s][c], 0, 0, 0);
    }
    float aS[4], aD[4];
    #pragma unroll
    for (int c = 0; c < 4; ++c) { aS[c] = att_s[c * 16 + col]; aD[c] = att_d[c * 16 + col]; }
    #pragma unroll
    for (int s = 0; s < 2; ++s) {
        #pragma unroll
        for (int c = 0; c < 4; ++c) {
            #pragma unroll
            for (int r = 0; r < 4; ++r) {
                float own = acc[s][c][r];
                float par = SWZ_F(own, 0x041F);
                int node = nodebase + s * 16 + quad * 4 + r;
                if (!(lane & 1) && node < n)
                    hp[(size_t)node * 32 + c * 8 + (col >> 1)] =
                        f2bf(own) | (f2bf(par) << 16);
            }
        }
        #pragma unroll
        for (int r = 0; r < 4; ++r) {
            float ps = 0.f, pd = 0.f;
            #pragma unroll
            for (int c = 0; c < 4; ++c) {
                ps = fmaf(acc[s][c][r], aS[c], ps);
                pd = fmaf(acc[s][c][r], aD[c], pd);
            }
            ps += SWZ_F(ps, 0x041F); pd += SWZ_F(pd, 0x041F);
            ps += SWZ_F(ps, 0x081F); pd += SWZ_F(pd, 0x081F);
            ps += SWZ_F(ps, 0x101F); pd += SWZ_F(pd, 0x101F);
            ps += SWZ_F(ps, 0x201F); pd += SWZ_F(pd, 0x201F);
            int node = nodebase + s * 16 + quad * 4 + r;
            if (col == 0 && node < n) { as_[node] = ps; ad_[node] = pd; }
        }
    }
}

// ---------------------------------------------------------------------------
// Aggregation layer1: wave per dst node, lane owns channels (2l, 2l+1),
// head = lane>>4. 32-edge chunks mirrored into both halves; per-(edge,head)
// weights via lane-specialized exp + ds_swizzle broadcast.
#define A1_G8(B, K0) { \
    int t0 = SWZ_I(myc, (((B)+(K0)+0)<<5)); \
    int t1 = SWZ_I(myc, (((B)+(K0)+1)<<5)); \
    int t2 = SWZ_I(myc, (((B)+(K0)+2)<<5)); \
    int t3 = SWZ_I(myc, (((B)+(K0)+3)<<5)); \
    int t4 = SWZ_I(myc, (((B)+(K0)+4)<<5)); \
    int t5 = SWZ_I(myc, (((B)+(K0)+5)<<5)); \
    int t6 = SWZ_I(myc, (((B)+(K0)+6)<<5)); \
    int t7 = SWZ_I(myc, (((B)+(K0)+7)<<5)); \
    unsigned v0 = hp[(size_t)t0 * 64 + lane]; \
    unsigned v1 = hp[(size_t)t1 * 64 + lane]; \
    unsigned v2 = hp[(size_t)t2 * 64 + lane]; \
    unsigned v3 = hp[(size_t)t3 * 64 + lane]; \
    unsigned v4 = hp[(size_t)t4 * 64 + lane]; \
    unsigned v5 = hp[(size_t)t5 * 64 + lane]; \
    unsigned v6 = hp[(size_t)t6 * 64 + lane]; \
    unsigned v7 = hp[(size_t)t7 * 64 + lane]; \
    float q0 = SWZ_F(ew, ((((K0)+0)<<5)|0x10)); \
    float q1 = SWZ_F(ew, ((((K0)+1)<<5)|0x10)); \
    float q2 = SWZ_F(ew, ((((K0)+2)<<5)|0x10)); \
    float q3 = SWZ_F(ew, ((((K0)+3)<<5)|0x10)); \
    float q4 = SWZ_F(ew, ((((K0)+4)<<5)|0x10)); \
    float q5 = SWZ_F(ew, ((((K0)+5)<<5)|0x10)); \
    float q6 = SWZ_F(ew, ((((K0)+6)<<5)|0x10)); \
    float q7 = SWZ_F(ew, ((((K0)+7)<<5)|0x10)); \
    s += q0; acc0 = fmaf(q0, bflo(v0), acc0); acc1 = fmaf(q0, bfhi(v0), acc1); \
    s += q1; acc0 = fmaf(q1, bflo(v1), acc0); acc1 = fmaf(q1, bfhi(v1), acc1); \
    s += q2; acc0 = fmaf(q2, bflo(v2), acc0); acc1 = fmaf(q2, bfhi(v2), acc1); \
    s += q3; acc0 = fmaf(q3, bflo(v3), acc0); acc1 = fmaf(q3, bfhi(v3), acc1); \
    s += q4; acc0 = fmaf(q4, bflo(v4), acc0); acc1 = fmaf(q4, bfhi(v4), acc1); \
    s += q5; acc0 = fmaf(q5, bflo(v5), acc0); acc1 = fmaf(q5, bfhi(v5), acc1); \
    s += q6; acc0 = fmaf(q6, bflo(v6), acc0); acc1 = fmaf(q6, bfhi(v6), acc1); \
    s += q7; acc0 = fmaf(q7, bflo(v7), acc0); acc1 = fmaf(q7, bfhi(v7), acc1); }

#define A1_SUB(B) { \
    int sspec = SWZ_I(myc, (((B)<<5) | 0x0F)); \
    float ee_ = as_[(size_t)sspec * 4 + head] + adv; \
    ee_ = fmaxf(ee_, 0.2f * ee_); \
    float ew = ((cb + (B) + (lane & 15)) < end) ? __expf(ee_) : 0.f; \
    A1_G8(B, 0) \
    if (m > (B) + 8) A1_G8(B, 8) }

__global__ __launch_bounds__(256) void agg1_kernel(
        const unsigned* __restrict__ hp, const float* __restrict__ as_,
        const float* __restrict__ ad_, const int* __restrict__ row_ptr,
        const int* __restrict__ col, const float* __restrict__ bias,
        unsigned* __restrict__ outp, int n) {
    int wid = (blockIdx.x * 256 + threadIdx.x) >> 6;
    int lane = threadIdx.x & 63;
    if (wid >= n) return;
    int node = wid;
    int head = lane >> 4;
    float adv = ad_[(size_t)node * 4 + head];
    float e0 = as_[(size_t)node * 4 + head] + adv;
    e0 = fmaxf(e0, 0.2f * e0);
    float w0 = __expf(e0);
    float s = w0;
    unsigned u0 = hp[(size_t)node * 64 + lane];
    float acc0 = w0 * bflo(u0), acc1 = w0 * bfhi(u0);
    int beg = row_ptr[node], end = row_ptr[node + 1];
    for (int cb = beg; cb < end; cb += 32) {
        int m = end - cb; if (m > 32) m = 32;
        int ci = cb + (lane & 31);
        int myc = col[(ci < end) ? ci : (end - 1)];
        A1_SUB(0)
        if (m > 16) A1_SUB(16)
    }
    float inv = 1.0f / (s + 1e-16f);
    float2 b = *(const float2*)&bias[lane * 2];
    outp[(size_t)node * 64 + lane] =
        f2bf(acc0 * inv + b.x) | (f2bf(acc1 * inv + b.y) << 16);
}

// Aggregation layer2: wave per dst node; halves process even/odd edges.
#define A2_G4(K0) { \
    int t0 = SWZ_I(myc, (((K0)+0)<<5)); \
    int t1 = SWZ_I(myc, (((K0)+1)<<5)); \
    int t2 = SWZ_I(myc, (((K0)+2)<<5)); \
    int t3 = SWZ_I(myc, (((K0)+3)<<5)); \
    unsigned v0 = hp[(size_t)t0 * 32 + wrd]; \
    unsigned v1 = hp[(size_t)t1 * 32 + wrd]; \
    unsigned v2 = hp[(size_t)t2 * 32 + wrd]; \
    unsigned v3 = hp[(size_t)t3 * 32 + wrd]; \
    float q0 = SWZ_F(ew, (((K0)+0)<<5)); \
    float q1 = SWZ_F(ew, (((K0)+1)<<5)); \
    float q2 = SWZ_F(ew, (((K0)+2)<<5)); \
    float q3 = SWZ_F(ew, (((K0)+3)<<5)); \
    s += q0; acc0 = fmaf(q0, bflo(v0), acc0); acc1 = fmaf(q0, bfhi(v0), acc1); \
    s += q1; acc0 = fmaf(q1, bflo(v1), acc0); acc1 = fmaf(q1, bfhi(v1), acc1); \
    s += q2; acc0 = fmaf(q2, bflo(v2), acc0); acc1 = fmaf(q2, bfhi(v2), acc1); \
    s += q3; acc0 = fmaf(q3, bflo(v3), acc0); acc1 = fmaf(q3, bfhi(v3), acc1); }

__global__ __launch_bounds__(256) void agg2_kernel(
        const unsigned* __restrict__ hp, const float* __restrict__ as_,
        const float* __restrict__ ad_, const int* __restrict__ row_ptr,
        const int* __restrict__ col, const float* __restrict__ bias,
        float* __restrict__ out, int n) {
    int wid = (blockIdx.x * 256 + threadIdx.x) >> 6;
    int lane = threadIdx.x & 63;
    if (wid >= n) return;
    int node = wid;
    int half = lane >> 5, wrd = lane & 31;
    float adv = ad_[node];
    float s = 0.f, acc0 = 0.f, acc1 = 0.f;
    {
        float e = as_[node] + adv; e = fmaxf(e, 0.2f * e);
        float w = __expf(e);
        if (half == 0) {
            unsigned u = hp[(size_t)node * 32 + wrd];
            s = w; acc0 = w * bflo(u); acc1 = w * bfhi(u);
        }
    }
    int beg = row_ptr[node], end = row_ptr[node + 1];
    for (int cb = beg; cb < end; cb += 64) {
        int m = end - cb; if (m > 64) m = 64;
        int idx = cb + 2 * (lane & 31) + half;
        int myc = col[(idx < end) ? idx : (end - 1)];
        float ee = as_[myc] + adv; ee = fmaxf(ee, 0.2f * ee);
        float ew = (idx < end) ? __expf(ee) : 0.f;
        A2_G4(0)
        if (m > 8)  A2_G4(4)
        if (m > 16) A2_G4(8)
        if (m > 24) A2_G4(12)
        if (m > 32) {
            A2_G4(16)
            if (m > 40) A2_G4(20)
            if (m > 48) A2_G4(24)
            if (m > 56) A2_G4(28)
        }
    }
    s += __shfl_xor(s, 32);
    acc0 += __shfl_xor(acc0, 32);
    acc1 += __shfl_xor(acc1, 32);
    if (half == 0) {
        float inv = 1.0f / (s + 1e-16f);
        float2 b = *(const float2*)&bias[wrd * 2];
        *(float2*)&out[(size_t)node * 64 + wrd * 2] =
            make_float2(acc0 * inv + b.x, acc1 * inv + b.y);
    }
}

// ---------------------------------------------------------------------------
extern "C" void kernel_launch(void* const* d_in, const int* in_sizes, int n_in,
                              void* d_out, int out_size, void* d_ws, size_t ws_size,
                              hipStream_t stream) {
    const float* inp   = (const float*)d_in[0];
    const int*   ei    = (const int*)d_in[1];
    const float* W1    = (const float*)d_in[2];
    const float* atts1 = (const float*)d_in[3];
    const float* attd1 = (const float*)d_in[4];
    const float* bias1 = (const float*)d_in[5];
    const float* W2    = (const float*)d_in[6];
    const float* atts2 = (const float*)d_in[7];
    const float* attd2 = (const float*)d_in[8];
    const float* bias2 = (const float*)d_in[9];
    float* out = (float*)d_out;

    const int N = N_NODES;
    const int E = in_sizes[1] / 2;

    const int EB = (E + 2047) / 2048;          // edge blocks
    const int K = 256 * EB;                    // ghBM length
    const int nbK = (K + SCAN_BLOCK - 1) / SCAN_BLOCK;   // <=256 for E<=2M

    unsigned* h1p = (unsigned*)d_ws;               // N*64 uints (layer2 reuses N*32)
    unsigned* x1p = h1p + (size_t)N * 64;          // N*64 uints (bf16-packed x1)
    float* as1 = (float*)(x1p + (size_t)N * 64);   // N*4
    float* ad1 = as1 + (size_t)N * 4;              // N*4
    int* row_ptr  = (int*)(ad1 + (size_t)N * 4);   // N+1
    int* col      = row_ptr + N + 1;               // E
    int* ghBM     = col + E;                       // 256*EB
    int* bsum     = ghBM + K;                      // 256
    int* flag     = bsum + 256;                    // 1
    unsigned* tmp = x1p;                           // E uints, aliases x1p (dead until agg1)

    detect_kernel<<<1, 64, 0, stream>>>(ei, flag);

    // atomic-free CSR build
    histA_kernel<<<EB, 256, 0, stream>>>(ei, flag, ghBM, EB, E);
    pscanA_kernel<<<nbK, SCAN_BLOCK, 0, stream>>>(ghBM, bsum, K);
    pscanB_kernel<<<1, 256, 0, stream>>>(bsum, nbK);
    pscanC_kernel<<<nbK, SCAN_BLOCK, 0, stream>>>(ghBM, bsum, K);
    scatterB_kernel<<<EB, 256, 0, stream>>>(ei, flag, ghBM, EB, tmp, E);
    bucketC_kernel<<<256, 256, 0, stream>>>(tmp, ghBM, EB, row_ptr, col, E, N);

    // layer 1
    gemm1_kernel<<<(N + 127) / 128, 256, 0, stream>>>(inp, W1, atts1, attd1, h1p, as1, ad1, N);
    agg1_kernel<<<(N + 3) / 4, 256, 0, stream>>>(h1p, as1, ad1, row_ptr, col, bias1, x1p, N);

    // layer 2 (h2p aliases h1p; as2/ad2 alias as1/ad1)
    gemm2_kernel<<<(N + 127) / 128, 256, 0, stream>>>(x1p, W2, atts2, attd2, h1p, as1, ad1, N);
    agg2_kernel<<<(N + 3) / 4, 256, 0, stream>>>(h1p, as1, ad1, row_ptr, col, bias2, out, N);
}

// Round 10
// 210.179 us; speedup vs baseline: 1.3507x; 1.0507x over previous
//
#include <hip/hip_runtime.h>

#define N_NODES 100000
#define F1 128
#define NCLS 64
#define EPB 8   // edges per thread in edge-pass kernels

typedef __attribute__((ext_vector_type(8))) short bf16x8;
typedef __attribute__((ext_vector_type(4))) float f32x4;

__device__ __forceinline__ unsigned f2bf(float x) {
    unsigned u = __builtin_bit_cast(unsigned, x);
    u += 0x7fff + ((u >> 16) & 1);
    return u >> 16;
}
__device__ __forceinline__ float bflo(unsigned u) {
    return __builtin_bit_cast(float, u << 16);
}
__device__ __forceinline__ float bfhi(unsigned u) {
    return __builtin_bit_cast(float, u & 0xffff0000u);
}

// ds_swizzle helpers (offset BitMode: lane i reads ((i&and)|or)^xor, per 32-lane half)
#define SWZ_I(v, off) __builtin_amdgcn_ds_swizzle((v), (off))
#define SWZ_F(v, off) __builtin_bit_cast(float, __builtin_amdgcn_ds_swizzle(__builtin_bit_cast(int, (v)), (off)))

__device__ __forceinline__ int load_edge(const int* ei, int is64, long long idx) {
    return is64 ? ei[2 * idx] : ei[idx];
}

// Inline edge-dtype probe: wave 0 ballots on the first 64 odd int32 words
// (all zero <=> little-endian int64 with values < 2^31). P(false positive
// on genuine int32 data) ~ (1e-5)^64 ~ 0.
#define EDGE_PROBE(ei, s_is64, tid) { \
    int v_ = (ei)[2 * ((tid) & 63) + 1]; \
    unsigned long long b_ = __ballot(v_ == 0); \
    if ((tid) == 0) s_is64 = (b_ == ~0ull) ? 1 : 0; }

// ---------------------------------------------------------------------------
// Atomic-free CSR build: bucket = dst>>9 (256 buckets of 512 nodes).
// histA: per-block LDS histogram over buckets -> ghBM[bk*EB + blk].
__global__ __launch_bounds__(256) void histA_kernel(
        const int* __restrict__ ei, int* __restrict__ ghBM, int EB, int E) {
    __shared__ int bins[256];
    __shared__ int s_is64;
    int tid = threadIdx.x;
    bins[tid] = 0;
    EDGE_PROBE(ei, s_is64, tid)
    __syncthreads();
    int is64 = s_is64;
    long long base = (long long)blockIdx.x * 2048 + tid * EPB;
    int d[EPB];
    #pragma unroll
    for (int k = 0; k < EPB; ++k) {
        long long e = base + k;
        d[k] = (e < E) ? load_edge(ei, is64, (long long)E + e) : -1;
    }
    #pragma unroll
    for (int k = 0; k < EPB; ++k)
        if (d[k] >= 0) atomicAdd(&bins[d[k] >> 9], 1);
    __syncthreads();
    ghBM[(size_t)tid * EB + blockIdx.x] = bins[tid];
}

// pscanA: block-local exclusive scan over ghBM (length K), bsum[blk] = total.
#define SCAN_BLOCK 1024
__global__ void pscanA_kernel(int* __restrict__ g, int* __restrict__ bsum, int K) {
    __shared__ int sm[SCAN_BLOCK];
    int tid = threadIdx.x;
    int i = blockIdx.x * SCAN_BLOCK + tid;
    int v = (i < K) ? g[i] : 0;
    sm[tid] = v;
    __syncthreads();
    for (int off = 1; off < SCAN_BLOCK; off <<= 1) {
        int t = (tid >= off) ? sm[tid - off] : 0;
        __syncthreads();
        sm[tid] += t;
        __syncthreads();
    }
    if (i < K) g[i] = sm[tid] - v;
    if (tid == SCAN_BLOCK - 1) bsum[blockIdx.x] = sm[tid];
}

// pscanC: each block scans bsum (<=256 entries) in LDS, adds its prefix.
__global__ void pscanC_kernel(int* __restrict__ g, const int* __restrict__ bsum,
                              int K, int nb) {
    __shared__ int sm[256];
    int tid = threadIdx.x;
    if (tid < 256) sm[tid] = (tid < nb) ? bsum[tid] : 0;
    __syncthreads();
    for (int off = 1; off < 256; off <<= 1) {
        int t = (tid < 256 && tid >= off) ? sm[tid - off] : 0;
        __syncthreads();
        if (tid < 256) sm[tid] += t;
        __syncthreads();
    }
    int pre = (blockIdx.x == 0) ? 0 : sm[blockIdx.x - 1];
    int i = blockIdx.x * SCAN_BLOCK + tid;
    if (i < K) g[i] += pre;
}

// ---------------------------------------------------------------------------
// FUSED: blocks [0,EB) = scatterB (bucket-partition edges, LDS rank, packed
// write, zero global atomics); blocks [EB, EB+nG1) = layer1 MFMA GEMM.
// Streaming scatter waves and MFMA waves co-schedule on the CUs.
__global__ __launch_bounds__(256) void scatgemm1_kernel(
        const int* __restrict__ ei, const int* __restrict__ ghBM, int EB,
        unsigned* __restrict__ tmp, int E,
        const float* __restrict__ x, const float* __restrict__ W,
        const float* __restrict__ att_s, const float* __restrict__ att_d,
        unsigned* __restrict__ hp, float* __restrict__ as_, float* __restrict__ ad_, int n) {
    __shared__ uint4 WtS[2048];                 // 32 KB (gemm); scatter uses 1 KB
    __shared__ int s_is64;
    int tid = threadIdx.x;
    if (blockIdx.x < (unsigned)EB) {
        // ---------------- scatter part ----------------
        int* base = (int*)WtS;
        base[tid] = ghBM[(size_t)tid * EB + blockIdx.x];
        EDGE_PROBE(ei, s_is64, tid)
        __syncthreads();
        int is64 = s_is64;
        long long eb = (long long)blockIdx.x * 2048 + tid * EPB;
        int d[EPB], s[EPB];
        #pragma unroll
        for (int k = 0; k < EPB; ++k) {
            long long e = eb + k;
            d[k] = (e < E) ? load_edge(ei, is64, (long long)E + e) : -1;
        }
        #pragma unroll
        for (int k = 0; k < EPB; ++k) {
            long long e = eb + k;
            s[k] = (e < E) ? load_edge(ei, is64, e) : 0;
        }
        #pragma unroll
        for (int k = 0; k < EPB; ++k) {
            if (d[k] >= 0) {
                int pos = atomicAdd(&base[d[k] >> 9], 1);
                tmp[pos] = (unsigned)s[k] | ((unsigned)(d[k] & 511) << 17);
            }
        }
        return;
    }
    // ---------------- gemm1 part ----------------
    unsigned* Wt = (unsigned*)WtS;
    {   // stage W^T (convert f32->bf16), swizzle bytecol ^= (ch&7)<<4
        int ch = tid & 127, fb = tid >> 7;
        #pragma unroll
        for (int j8 = 0; j8 < 8; ++j8) {
            int f0 = fb * 64 + j8 * 8;
            unsigned pk[4];
            #pragma unroll
            for (int p = 0; p < 4; ++p) {
                float lo = W[(size_t)(f0 + 2 * p) * 128 + ch];
                float hi = W[(size_t)(f0 + 2 * p + 1) * 128 + ch];
                pk[p] = f2bf(lo) | (f2bf(hi) << 16);
            }
            int bcol = (f0 * 2) ^ ((ch & 7) << 4);
            *(uint4*)&Wt[ch * 64 + (bcol >> 2)] = *(uint4*)pk;
        }
    }
    __syncthreads();
    int lane = tid & 63, w = tid >> 6;
    int col = lane & 15, quad = lane >> 4;
    int nodebase = (blockIdx.x - EB) * 128 + w * 32;
    bf16x8 a[2][4];
    #pragma unroll
    for (int s = 0; s < 2; ++s) {
        int node = nodebase + s * 16 + col;
        const float* xr = x + (size_t)node * 128;
        bool v = node < n;
        #pragma unroll
        for (int kk = 0; kk < 4; ++kk) {
            float4 lo = v ? *(const float4*)&xr[kk * 32 + quad * 8]
                          : make_float4(0.f, 0.f, 0.f, 0.f);
            float4 hi = v ? *(const float4*)&xr[kk * 32 + quad * 8 + 4]
                          : make_float4(0.f, 0.f, 0.f, 0.f);
            unsigned pk[4];
            pk[0] = f2bf(lo.x) | (f2bf(lo.y) << 16);
            pk[1] = f2bf(lo.z) | (f2bf(lo.w) << 16);
            pk[2] = f2bf(hi.x) | (f2bf(hi.y) << 16);
            pk[3] = f2bf(hi.z) | (f2bf(hi.w) << 16);
            a[s][kk] = *(bf16x8*)pk;
        }
    }
    f32x4 acc[2][8] = {};
    #pragma unroll
    for (int c = 0; c < 8; ++c) {
        int brow = c * 16 + col;
        bf16x8 b[4];
        #pragma unroll
        for (int kk = 0; kk < 4; ++kk) {
            int bcol = (kk * 64 + quad * 16) ^ ((brow & 7) << 4);
            b[kk] = *(bf16x8*)&Wt[brow * 64 + (bcol >> 2)];
        }
        #pragma unroll
        for (int s = 0; s < 2; ++s)
            #pragma unroll
            for (int kk = 0; kk < 4; ++kk)
                acc[s][c] = __builtin_amdgcn_mfma_f32_16x16x32_bf16(a[s][kk], b[kk], acc[s][c], 0, 0, 0);
    }
    float aS[8], aD[8];
    #pragma unroll
    for (int c = 0; c < 8; ++c) { aS[c] = att_s[c * 16 + col]; aD[c] = att_d[c * 16 + col]; }
    #pragma unroll
    for (int s = 0; s < 2; ++s) {
        #pragma unroll
        for (int c = 0; c < 8; ++c) {
            #pragma unroll
            for (int r = 0; r < 4; ++r) {
                float own = acc[s][c][r];
                float par = SWZ_F(own, 0x041F);        // lane ^ 1
                int node = nodebase + s * 16 + quad * 4 + r;
                if (!(lane & 1) && node < n)
                    hp[(size_t)node * 64 + c * 8 + (col >> 1)] =
                        f2bf(own) | (f2bf(par) << 16);
            }
        }
        #pragma unroll
        for (int h = 0; h < 4; ++h) {
            #pragma unroll
            for (int r = 0; r < 4; ++r) {
                float ps = acc[s][2 * h][r] * aS[2 * h] + acc[s][2 * h + 1][r] * aS[2 * h + 1];
                float pd = acc[s][2 * h][r] * aD[2 * h] + acc[s][2 * h + 1][r] * aD[2 * h + 1];
                ps += SWZ_F(ps, 0x041F); pd += SWZ_F(pd, 0x041F);
                ps += SWZ_F(ps, 0x081F); pd += SWZ_F(pd, 0x081F);
                ps += SWZ_F(ps, 0x101F); pd += SWZ_F(pd, 0x101F);
                ps += SWZ_F(ps, 0x201F); pd += SWZ_F(pd, 0x201F);
                int node = nodebase + s * 16 + quad * 4 + r;
                if (col == 0 && node < n) {
                    as_[(size_t)node * 4 + h] = ps;
                    ad_[(size_t)node * 4 + h] = pd;
                }
            }
        }
    }
}

// bucketC: one block per bucket. LDS count over 512 local nodes -> LDS scan
// -> row_ptr (global CSR offsets) + rank-scatter col.
__global__ __launch_bounds__(256) void bucketC_kernel(
        const unsigned* __restrict__ tmp, const int* __restrict__ ghBM, int EB,
        int* __restrict__ row_ptr, int* __restrict__ col, int E, int n) {
    __shared__ int lb[512];
    __shared__ int lo[512];
    __shared__ int sm[256];
    int bk = blockIdx.x;
    int tid = threadIdx.x;
    int gbase = ghBM[(size_t)bk * EB];
    int gend = (bk == 255) ? E : ghBM[(size_t)(bk + 1) * EB];
    int cnt = gend - gbase;
    lb[tid] = 0; lb[tid + 256] = 0;
    __syncthreads();
    for (int i = tid; i < cnt; i += 256)
        atomicAdd(&lb[tmp[gbase + i] >> 17], 1);
    __syncthreads();
    int p = lb[2 * tid], q = lb[2 * tid + 1];
    int ps = p + q;
    sm[tid] = ps;
    __syncthreads();
    for (int off = 1; off < 256; off <<= 1) {
        int t = (tid >= off) ? sm[tid - off] : 0;
        __syncthreads();
        sm[tid] += t;
        __syncthreads();
    }
    int excl = sm[tid] - ps;
    int e0 = excl, e1 = excl + p;
    lo[2 * tid] = e0; lo[2 * tid + 1] = e1;
    int v0 = bk * 512 + 2 * tid;
    if (v0 <= n) row_ptr[v0] = gbase + e0;
    if (v0 + 1 <= n) row_ptr[v0 + 1] = gbase + e1;
    __syncthreads();
    for (int i = tid; i < cnt; i += 256) {
        unsigned v = tmp[gbase + i];
        int r = atomicAdd(&lo[v >> 17], 1);
        col[gbase + r] = (int)(v & 0x1FFFFu);
    }
}

// ---------------------------------------------------------------------------
// Layer2 GEMM via MFMA bf16: [N,128(bf16-packed)]x[128,64].
__global__ __launch_bounds__(256) void gemm2_kernel(
        const unsigned* __restrict__ xp, const float* __restrict__ W,
        const float* __restrict__ att_s, const float* __restrict__ att_d,
        unsigned* __restrict__ hp, float* __restrict__ as_, float* __restrict__ ad_, int n) {
    __shared__ uint4 WtS[1024];                 // 16 KB: Wt[64ch][128k] bf16
    unsigned* Wt = (unsigned*)WtS;
    int tid = threadIdx.x;
    {   // stage W2^T
        int ch = tid & 63, fb = tid >> 6;
        #pragma unroll
        for (int j8 = 0; j8 < 4; ++j8) {
            int f0 = fb * 32 + j8 * 8;
            unsigned pk[4];
            #pragma unroll
            for (int p = 0; p < 4; ++p) {
                float lo = W[(size_t)(f0 + 2 * p) * 64 + ch];
                float hi = W[(size_t)(f0 + 2 * p + 1) * 64 + ch];
                pk[p] = f2bf(lo) | (f2bf(hi) << 16);
            }
            int bcol = (f0 * 2) ^ ((ch & 7) << 4);
            *(uint4*)&Wt[ch * 64 + (bcol >> 2)] = *(uint4*)pk;
        }
    }
    __syncthreads();
    int lane = tid & 63, w = tid >> 6;
    int col = lane & 15, quad = lane >> 4;
    int nodebase = blockIdx.x * 128 + w * 32;
    bf16x8 a[2][4];
    #pragma unroll
    for (int s = 0; s < 2; ++s) {
        int node = nodebase + s * 16 + col;
        bool v = node < n;
        #pragma unroll
        for (int kk = 0; kk < 4; ++kk) {
            uint4 u = v ? *(const uint4*)&xp[(size_t)node * 64 + kk * 16 + quad * 4]
                        : make_uint4(0, 0, 0, 0);
            a[s][kk] = *(bf16x8*)&u;
        }
    }
    f32x4 acc[2][4] = {};
    #pragma unroll
    for (int c = 0; c < 4; ++c) {
        int brow = c * 16 + col;
        bf16x8 b[4];
        #pragma unroll
        for (int kk = 0; kk < 4; ++kk) {
            int bcol = (kk * 64 + quad * 16) ^ ((brow & 7) << 4);
            b[kk] = *(bf16x8*)&Wt[brow * 64 + (bcol >> 2)];
        }
        #pragma unroll
        for (int s = 0; s < 2; ++s)
            #pragma unroll
            for (int kk = 0; kk < 4; ++kk)
                acc[s][c] = __builtin_amdgcn_mfma_f32_16x16x32_bf16(a[s][kk], b[kk], acc[s][c], 0, 0, 0);
    }
    float aS[4], aD[4];
    #pragma unroll
    for (int c = 0; c < 4; ++c) { aS[c] = att_s[c * 16 + col]; aD[c] = att_d[c * 16 + col]; }
    #pragma unroll
    for (int s = 0; s < 2; ++s) {
        #pragma unroll
        for (int c = 0; c < 4; ++c) {
            #pragma unroll
            for (int r = 0; r < 4; ++r) {
                float own = acc[s][c][r];
                float par = SWZ_F(own, 0x041F);
                int node = nodebase + s * 16 + quad * 4 + r;
                if (!(lane & 1) && node < n)
                    hp[(size_t)node * 32 + c * 8 + (col >> 1)] =
                        f2bf(own) | (f2bf(par) << 16);
            }
        }
        #pragma unroll
        for (int r = 0; r < 4; ++r) {
            float ps = 0.f, pd = 0.f;
            #pragma unroll
            for (int c = 0; c < 4; ++c) {
                ps = fmaf(acc[s][c][r], aS[c], ps);
                pd = fmaf(acc[s][c][r], aD[c], pd);
            }
            ps += SWZ_F(ps, 0x041F); pd += SWZ_F(pd, 0x041F);
            ps += SWZ_F(ps, 0x081F); pd += SWZ_F(pd, 0x081F);
            ps += SWZ_F(ps, 0x101F); pd += SWZ_F(pd, 0x101F);
            ps += SWZ_F(ps, 0x201F); pd += SWZ_F(pd, 0x201F);
            int node = nodebase + s * 16 + quad * 4 + r;
            if (col == 0 && node < n) { as_[node] = ps; ad_[node] = pd; }
        }
    }
}

// ---------------------------------------------------------------------------
// Aggregation layer1: wave per dst node, lane owns channels (2l, 2l+1),
// head = lane>>4. 32-edge chunks mirrored into both halves; per-(edge,head)
// weights via lane-specialized exp + ds_swizzle broadcast.
#define A1_G8(B, K0) { \
    int t0 = SWZ_I(myc, (((B)+(K0)+0)<<5)); \
    int t1 = SWZ_I(myc, (((B)+(K0)+1)<<5)); \
    int t2 = SWZ_I(myc, (((B)+(K0)+2)<<5)); \
    int t3 = SWZ_I(myc, (((B)+(K0)+3)<<5)); \
    int t4 = SWZ_I(myc, (((B)+(K0)+4)<<5)); \
    int t5 = SWZ_I(myc, (((B)+(K0)+5)<<5)); \
    int t6 = SWZ_I(myc, (((B)+(K0)+6)<<5)); \
    int t7 = SWZ_I(myc, (((B)+(K0)+7)<<5)); \
    unsigned v0 = hp[(size_t)t0 * 64 + lane]; \
    unsigned v1 = hp[(size_t)t1 * 64 + lane]; \
    unsigned v2 = hp[(size_t)t2 * 64 + lane]; \
    unsigned v3 = hp[(size_t)t3 * 64 + lane]; \
    unsigned v4 = hp[(size_t)t4 * 64 + lane]; \
    unsigned v5 = hp[(size_t)t5 * 64 + lane]; \
    unsigned v6 = hp[(size_t)t6 * 64 + lane]; \
    unsigned v7 = hp[(size_t)t7 * 64 + lane]; \
    float q0 = SWZ_F(ew, ((((K0)+0)<<5)|0x10)); \
    float q1 = SWZ_F(ew, ((((K0)+1)<<5)|0x10)); \
    float q2 = SWZ_F(ew, ((((K0)+2)<<5)|0x10)); \
    float q3 = SWZ_F(ew, ((((K0)+3)<<5)|0x10)); \
    float q4 = SWZ_F(ew, ((((K0)+4)<<5)|0x10)); \
    float q5 = SWZ_F(ew, ((((K0)+5)<<5)|0x10)); \
    float q6 = SWZ_F(ew, ((((K0)+6)<<5)|0x10)); \
    float q7 = SWZ_F(ew, ((((K0)+7)<<5)|0x10)); \
    s += q0; acc0 = fmaf(q0, bflo(v0), acc0); acc1 = fmaf(q0, bfhi(v0), acc1); \
    s += q1; acc0 = fmaf(q1, bflo(v1), acc0); acc1 = fmaf(q1, bfhi(v1), acc1); \
    s += q2; acc0 = fmaf(q2, bflo(v2), acc0); acc1 = fmaf(q2, bfhi(v2), acc1); \
    s += q3; acc0 = fmaf(q3, bflo(v3), acc0); acc1 = fmaf(q3, bfhi(v3), acc1); \
    s += q4; acc0 = fmaf(q4, bflo(v4), acc0); acc1 = fmaf(q4, bfhi(v4), acc1); \
    s += q5; acc0 = fmaf(q5, bflo(v5), acc0); acc1 = fmaf(q5, bfhi(v5), acc1); \
    s += q6; acc0 = fmaf(q6, bflo(v6), acc0); acc1 = fmaf(q6, bfhi(v6), acc1); \
    s += q7; acc0 = fmaf(q7, bflo(v7), acc0); acc1 = fmaf(q7, bfhi(v7), acc1); }

#define A1_SUB(B) { \
    int sspec = SWZ_I(myc, (((B)<<5) | 0x0F)); \
    float ee_ = as_[(size_t)sspec * 4 + head] + adv; \
    ee_ = fmaxf(ee_, 0.2f * ee_); \
    float ew = ((cb + (B) + (lane & 15)) < end) ? __expf(ee_) : 0.f; \
    A1_G8(B, 0) \
    if (m > (B) + 8) A1_G8(B, 8) }

__global__ __launch_bounds__(256) void agg1_kernel(
        const unsigned* __restrict__ hp, const float* __restrict__ as_,
        const float* __restrict__ ad_, const int* __restrict__ row_ptr,
        const int* __restrict__ col, const float* __restrict__ bias,
        unsigned* __restrict__ outp, int n) {
    int wid = (blockIdx.x * 256 + threadIdx.x) >> 6;
    int lane = threadIdx.x & 63;
    if (wid >= n) return;
    int node = wid;
    int head = lane >> 4;
    float adv = ad_[(size_t)node * 4 + head];
    float e0 = as_[(size_t)node * 4 + head] + adv;
    e0 = fmaxf(e0, 0.2f * e0);
    float w0 = __expf(e0);
    float s = w0;
    unsigned u0 = hp[(size_t)node * 64 + lane];
    float acc0 = w0 * bflo(u0), acc1 = w0 * bfhi(u0);
    int beg = row_ptr[node], end = row_ptr[node + 1];
    for (int cb = beg; cb < end; cb += 32) {
        int m = end - cb; if (m > 32) m = 32;
        int ci = cb + (lane & 31);
        int myc = col[(ci < end) ? ci : (end - 1)];
        A1_SUB(0)
        if (m > 16) A1_SUB(16)
    }
    float inv = 1.0f / (s + 1e-16f);
    float2 b = *(const float2*)&bias[lane * 2];
    outp[(size_t)node * 64 + lane] =
        f2bf(acc0 * inv + b.x) | (f2bf(acc1 * inv + b.y) << 16);
}

// Aggregation layer2: wave per dst node; halves process even/odd edges.
#define A2_G4(K0) { \
    int t0 = SWZ_I(myc, (((K0)+0)<<5)); \
    int t1 = SWZ_I(myc, (((K0)+1)<<5)); \
    int t2 = SWZ_I(myc, (((K0)+2)<<5)); \
    int t3 = SWZ_I(myc, (((K0)+3)<<5)); \
    unsigned v0 = hp[(size_t)t0 * 32 + wrd]; \
    unsigned v1 = hp[(size_t)t1 * 32 + wrd]; \
    unsigned v2 = hp[(size_t)t2 * 32 + wrd]; \
    unsigned v3 = hp[(size_t)t3 * 32 + wrd]; \
    float q0 = SWZ_F(ew, (((K0)+0)<<5)); \
    float q1 = SWZ_F(ew, (((K0)+1)<<5)); \
    float q2 = SWZ_F(ew, (((K0)+2)<<5)); \
    float q3 = SWZ_F(ew, (((K0)+3)<<5)); \
    s += q0; acc0 = fmaf(q0, bflo(v0), acc0); acc1 = fmaf(q0, bfhi(v0), acc1); \
    s += q1; acc0 = fmaf(q1, bflo(v1), acc0); acc1 = fmaf(q1, bfhi(v1), acc1); \
    s += q2; acc0 = fmaf(q2, bflo(v2), acc0); acc1 = fmaf(q2, bfhi(v2), acc1); \
    s += q3; acc0 = fmaf(q3, bflo(v3), acc0); acc1 = fmaf(q3, bfhi(v3), acc1); }

__global__ __launch_bounds__(256) void agg2_kernel(
        const unsigned* __restrict__ hp, const float* __restrict__ as_,
        const float* __restrict__ ad_, const int* __restrict__ row_ptr,
        const int* __restrict__ col, const float* __restrict__ bias,
        float* __restrict__ out, int n) {
    int wid = (blockIdx.x * 256 + threadIdx.x) >> 6;
    int lane = threadIdx.x & 63;
    if (wid >= n) return;
    int node = wid;
    int half = lane >> 5, wrd = lane & 31;
    float adv = ad_[node];
    float s = 0.f, acc0 = 0.f, acc1 = 0.f;
    {
        float e = as_[node] + adv; e = fmaxf(e, 0.2f * e);
        float w = __expf(e);
        if (half == 0) {
            unsigned u = hp[(size_t)node * 32 + wrd];
            s = w; acc0 = w * bflo(u); acc1 = w * bfhi(u);
        }
    }
    int beg = row_ptr[node], end = row_ptr[node + 1];
    for (int cb = beg; cb < end; cb += 64) {
        int m = end - cb; if (m > 64) m = 64;
        int idx = cb + 2 * (lane & 31) + half;
        int myc = col[(idx < end) ? idx : (end - 1)];
        float ee = as_[myc] + adv; ee = fmaxf(ee, 0.2f * ee);
        float ew = (idx < end) ? __expf(ee) : 0.f;
        A2_G4(0)
        if (m > 8)  A2_G4(4)
        if (m > 16) A2_G4(8)
        if (m > 24) A2_G4(12)
        if (m > 32) {
            A2_G4(16)
            if (m > 40) A2_G4(20)
            if (m > 48) A2_G4(24)
            if (m > 56) A2_G4(28)
        }
    }
    s += __shfl_xor(s, 32);
    acc0 += __shfl_xor(acc0, 32);
    acc1 += __shfl_xor(acc1, 32);
    if (half == 0) {
        float inv = 1.0f / (s + 1e-16f);
        float2 b = *(const float2*)&bias[wrd * 2];
        *(float2*)&out[(size_t)node * 64 + wrd * 2] =
            make_float2(acc0 * inv + b.x, acc1 * inv + b.y);
    }
}

// ---------------------------------------------------------------------------
extern "C" void kernel_launch(void* const* d_in, const int* in_sizes, int n_in,
                              void* d_out, int out_size, void* d_ws, size_t ws_size,
                              hipStream_t stream) {
    const float* inp   = (const float*)d_in[0];
    const int*   ei    = (const int*)d_in[1];
    const float* W1    = (const float*)d_in[2];
    const float* atts1 = (const float*)d_in[3];
    const float* attd1 = (const float*)d_in[4];
    const float* bias1 = (const float*)d_in[5];
    const float* W2    = (const float*)d_in[6];
    const float* atts2 = (const float*)d_in[7];
    const float* attd2 = (const float*)d_in[8];
    const float* bias2 = (const float*)d_in[9];
    float* out = (float*)d_out;

    const int N = N_NODES;
    const int E = in_sizes[1] / 2;

    const int EB = (E + 2047) / 2048;          // edge blocks
    const int K = 256 * EB;                    // ghBM length
    const int nbK = (K + SCAN_BLOCK - 1) / SCAN_BLOCK;   // <=256 for E<=2M
    const int nG1 = (N + 127) / 128;           // gemm1 blocks

    unsigned* h1p = (unsigned*)d_ws;               // N*64 uints (layer2 reuses N*32)
    unsigned* x1p = h1p + (size_t)N * 64;          // N*64 uints (bf16-packed x1)
    float* as1 = (float*)(x1p + (size_t)N * 64);   // N*4
    float* ad1 = as1 + (size_t)N * 4;              // N*4
    int* row_ptr  = (int*)(ad1 + (size_t)N * 4);   // N+1
    int* col      = row_ptr + N + 1;               // E
    int* ghBM     = col + E;                       // 256*EB
    int* bsum     = ghBM + K;                      // 256
    unsigned* tmp = x1p;                           // E uints, aliases x1p (dead until agg1)

    // atomic-free CSR build (+ fused layer1 GEMM)
    histA_kernel<<<EB, 256, 0, stream>>>(ei, ghBM, EB, E);
    pscanA_kernel<<<nbK, SCAN_BLOCK, 0, stream>>>(ghBM, bsum, K);
    pscanC_kernel<<<nbK, SCAN_BLOCK, 0, stream>>>(ghBM, bsum, K, nbK);
    scatgemm1_kernel<<<EB + nG1, 256, 0, stream>>>(
        ei, ghBM, EB, tmp, E, inp, W1, atts1, attd1, h1p, as1, ad1, N);
    bucketC_kernel<<<256, 256, 0, stream>>>(tmp, ghBM, EB, row_ptr, col, E, N);

    agg1_kernel<<<(N + 3) / 4, 256, 0, stream>>>(h1p, as1, ad1, row_ptr, col, bias1, x1p, N);

    // layer 2 (h2p aliases h1p; as2/ad2 alias as1/ad1)
    gemm2_kernel<<<(N + 127) / 128, 256, 0, stream>>>(x1p, W2, atts2, attd2, h1p, as1, ad1, N);
    agg2_kernel<<<(N + 3) / 4, 256, 0, stream>>>(h1p, as1, ad1, row_ptr, col, bias2, out, N);
}

// Round 11
// 204.892 us; speedup vs baseline: 1.3856x; 1.0258x over previous
//
#include <hip/hip_runtime.h>

#define N_NODES 100000
#define F1 128
#define NCLS 64
#define EPB 8      // edges per thread in edge-pass kernels
#define BCAP 12288 // bucketC LDS staging capacity (edges)

typedef __attribute__((ext_vector_type(8))) short bf16x8;
typedef __attribute__((ext_vector_type(4))) float f32x4;

__device__ __forceinline__ unsigned f2bf(float x) {
    unsigned u = __builtin_bit_cast(unsigned, x);
    u += 0x7fff + ((u >> 16) & 1);
    return u >> 16;
}
__device__ __forceinline__ float bflo(unsigned u) {
    return __builtin_bit_cast(float, u << 16);
}
__device__ __forceinline__ float bfhi(unsigned u) {
    return __builtin_bit_cast(float, u & 0xffff0000u);
}

// ds_swizzle helpers (offset BitMode: lane i reads ((i&and)|or)^xor, per 32-lane half)
#define SWZ_I(v, off) __builtin_amdgcn_ds_swizzle((v), (off))
#define SWZ_F(v, off) __builtin_bit_cast(float, __builtin_amdgcn_ds_swizzle(__builtin_bit_cast(int, (v)), (off)))

__device__ __forceinline__ int load_edge(const int* ei, int is64, long long idx) {
    return is64 ? ei[2 * idx] : ei[idx];
}

// Inline edge-dtype probe: wave 0 ballots on the first 64 odd int32 words.
#define EDGE_PROBE(ei, s_is64, tid) { \
    int v_ = (ei)[2 * ((tid) & 63) + 1]; \
    unsigned long long b_ = __ballot(v_ == 0); \
    if ((tid) == 0) s_is64 = (b_ == ~0ull) ? 1 : 0; }

// 256-wide LDS inclusive scan of bsum; exclusive prefix for chunk j is
// (j==0) ? 0 : sm[j-1].
#define BSUM_SCAN(sm, bsum, nb, tid) { \
    sm[tid] = ((tid) < (nb)) ? bsum[tid] : 0; \
    __syncthreads(); \
    for (int off_ = 1; off_ < 256; off_ <<= 1) { \
        int t_ = ((tid) >= off_) ? sm[(tid) - off_] : 0; \
        __syncthreads(); \
        sm[tid] += t_; \
        __syncthreads(); \
    } }

// ---------------------------------------------------------------------------
// FUSED: blocks [0,EB) = per-block LDS bucket histogram (bucket = dst>>9);
// blocks [EB, EB+nG1) = layer1 MFMA GEMM. Independent work, co-scheduled.
__global__ __launch_bounds__(256) void histgemm1_kernel(
        const int* __restrict__ ei, int* __restrict__ ghBM, int EB, int E,
        const float* __restrict__ x, const float* __restrict__ W,
        const float* __restrict__ att_s, const float* __restrict__ att_d,
        unsigned* __restrict__ hp, float* __restrict__ as_, float* __restrict__ ad_, int n) {
    __shared__ uint4 WtS[2048];                 // 32 KB (gemm); hist uses 1 KB
    __shared__ int s_is64;
    int tid = threadIdx.x;
    if (blockIdx.x < (unsigned)EB) {
        // ---------------- hist part ----------------
        int* bins = (int*)WtS;
        bins[tid] = 0;
        EDGE_PROBE(ei, s_is64, tid)
        __syncthreads();
        int is64 = s_is64;
        long long base = (long long)blockIdx.x * 2048 + tid * EPB;
        int d[EPB];
        #pragma unroll
        for (int k = 0; k < EPB; ++k) {
            long long e = base + k;
            d[k] = (e < E) ? load_edge(ei, is64, (long long)E + e) : -1;
        }
        #pragma unroll
        for (int k = 0; k < EPB; ++k)
            if (d[k] >= 0) atomicAdd(&bins[d[k] >> 9], 1);
        __syncthreads();
        ghBM[(size_t)tid * EB + blockIdx.x] = bins[tid];
        return;
    }
    // ---------------- gemm1 part ----------------
    unsigned* Wt = (unsigned*)WtS;
    {   // stage W^T (convert f32->bf16), swizzle bytecol ^= (ch&7)<<4
        int ch = tid & 127, fb = tid >> 7;
        #pragma unroll
        for (int j8 = 0; j8 < 8; ++j8) {
            int f0 = fb * 64 + j8 * 8;
            unsigned pk[4];
            #pragma unroll
            for (int p = 0; p < 4; ++p) {
                float lo = W[(size_t)(f0 + 2 * p) * 128 + ch];
                float hi = W[(size_t)(f0 + 2 * p + 1) * 128 + ch];
                pk[p] = f2bf(lo) | (f2bf(hi) << 16);
            }
            int bcol = (f0 * 2) ^ ((ch & 7) << 4);
            *(uint4*)&Wt[ch * 64 + (bcol >> 2)] = *(uint4*)pk;
        }
    }
    __syncthreads();
    int lane = tid & 63, w = tid >> 6;
    int col = lane & 15, quad = lane >> 4;
    int nodebase = (blockIdx.x - EB) * 128 + w * 32;
    bf16x8 a[2][4];
    #pragma unroll
    for (int s = 0; s < 2; ++s) {
        int node = nodebase + s * 16 + col;
        const float* xr = x + (size_t)node * 128;
        bool v = node < n;
        #pragma unroll
        for (int kk = 0; kk < 4; ++kk) {
            float4 lo = v ? *(const float4*)&xr[kk * 32 + quad * 8]
                          : make_float4(0.f, 0.f, 0.f, 0.f);
            float4 hi = v ? *(const float4*)&xr[kk * 32 + quad * 8 + 4]
                          : make_float4(0.f, 0.f, 0.f, 0.f);
            unsigned pk[4];
            pk[0] = f2bf(lo.x) | (f2bf(lo.y) << 16);
            pk[1] = f2bf(lo.z) | (f2bf(lo.w) << 16);
            pk[2] = f2bf(hi.x) | (f2bf(hi.y) << 16);
            pk[3] = f2bf(hi.z) | (f2bf(hi.w) << 16);
            a[s][kk] = *(bf16x8*)pk;
        }
    }
    f32x4 acc[2][8] = {};
    #pragma unroll
    for (int c = 0; c < 8; ++c) {
        int brow = c * 16 + col;
        bf16x8 b[4];
        #pragma unroll
        for (int kk = 0; kk < 4; ++kk) {
            int bcol = (kk * 64 + quad * 16) ^ ((brow & 7) << 4);
            b[kk] = *(bf16x8*)&Wt[brow * 64 + (bcol >> 2)];
        }
        #pragma unroll
        for (int s = 0; s < 2; ++s)
            #pragma unroll
            for (int kk = 0; kk < 4; ++kk)
                acc[s][c] = __builtin_amdgcn_mfma_f32_16x16x32_bf16(a[s][kk], b[kk], acc[s][c], 0, 0, 0);
    }
    float aS[8], aD[8];
    #pragma unroll
    for (int c = 0; c < 8; ++c) { aS[c] = att_s[c * 16 + col]; aD[c] = att_d[c * 16 + col]; }
    #pragma unroll
    for (int s = 0; s < 2; ++s) {
        #pragma unroll
        for (int c = 0; c < 8; ++c) {
            #pragma unroll
            for (int r = 0; r < 4; ++r) {
                float own = acc[s][c][r];
                float par = SWZ_F(own, 0x041F);        // lane ^ 1
                int node = nodebase + s * 16 + quad * 4 + r;
                if (!(lane & 1) && node < n)
                    hp[(size_t)node * 64 + c * 8 + (col >> 1)] =
                        f2bf(own) | (f2bf(par) << 16);
            }
        }
        #pragma unroll
        for (int h = 0; h < 4; ++h) {
            #pragma unroll
            for (int r = 0; r < 4; ++r) {
                float ps = acc[s][2 * h][r] * aS[2 * h] + acc[s][2 * h + 1][r] * aS[2 * h + 1];
                float pd = acc[s][2 * h][r] * aD[2 * h] + acc[s][2 * h + 1][r] * aD[2 * h + 1];
                ps += SWZ_F(ps, 0x041F); pd += SWZ_F(pd, 0x041F);
                ps += SWZ_F(ps, 0x081F); pd += SWZ_F(pd, 0x081F);
                ps += SWZ_F(ps, 0x101F); pd += SWZ_F(pd, 0x101F);
                ps += SWZ_F(ps, 0x201F); pd += SWZ_F(pd, 0x201F);
                int node = nodebase + s * 16 + quad * 4 + r;
                if (col == 0 && node < n) {
                    as_[(size_t)node * 4 + h] = ps;
                    ad_[(size_t)node * 4 + h] = pd;
                }
            }
        }
    }
}

// pscanA: block-local exclusive scan over ghBM (length K), bsum[blk] = total.
#define SCAN_BLOCK 1024
__global__ void pscanA_kernel(int* __restrict__ g, int* __restrict__ bsum, int K) {
    __shared__ int sm[SCAN_BLOCK];
    int tid = threadIdx.x;
    int i = blockIdx.x * SCAN_BLOCK + tid;
    int v = (i < K) ? g[i] : 0;
    sm[tid] = v;
    __syncthreads();
    for (int off = 1; off < SCAN_BLOCK; off <<= 1) {
        int t = (tid >= off) ? sm[tid - off] : 0;
        __syncthreads();
        sm[tid] += t;
        __syncthreads();
    }
    if (i < K) g[i] = sm[tid] - v;
    if (tid == SCAN_BLOCK - 1) bsum[blockIdx.x] = sm[tid];
}

// scatterB: finalize scan locally (bsum LDS scan), bucket-partition edges via
// LDS rank, packed write. Zero global atomics.
__global__ __launch_bounds__(256) void scatterB_kernel(
        const int* __restrict__ ei, const int* __restrict__ ghBM, int EB,
        const int* __restrict__ bsum, int nbK,
        unsigned* __restrict__ tmp, int E) {
    __shared__ int base[256];
    __shared__ int sm[256];
    __shared__ int s_is64;
    int tid = threadIdx.x;
    EDGE_PROBE(ei, s_is64, tid)
    BSUM_SCAN(sm, bsum, nbK, tid)
    {
        int idx = tid * EB + blockIdx.x;
        int chunk = idx >> 10;
        int pre = (chunk == 0) ? 0 : sm[chunk - 1];
        base[tid] = ghBM[(size_t)idx] + pre;
    }
    __syncthreads();
    int is64 = s_is64;
    long long eb = (long long)blockIdx.x * 2048 + tid * EPB;
    int d[EPB], s[EPB];
    #pragma unroll
    for (int k = 0; k < EPB; ++k) {
        long long e = eb + k;
        d[k] = (e < E) ? load_edge(ei, is64, (long long)E + e) : -1;
    }
    #pragma unroll
    for (int k = 0; k < EPB; ++k) {
        long long e = eb + k;
        s[k] = (e < E) ? load_edge(ei, is64, e) : 0;
    }
    #pragma unroll
    for (int k = 0; k < EPB; ++k) {
        if (d[k] >= 0) {
            int pos = atomicAdd(&base[d[k] >> 9], 1);
            tmp[pos] = (unsigned)s[k] | ((unsigned)(d[k] & 511) << 17);
        }
    }
}

// bucketC: one block per bucket; LDS-staged single pass (fallback: global
// 2-pass). LDS count over 512 local nodes -> scan -> row_ptr + ranked col.
__global__ __launch_bounds__(256) void bucketC_kernel(
        const unsigned* __restrict__ tmp, const int* __restrict__ ghBM, int EB,
        const int* __restrict__ bsum, int nbK,
        int* __restrict__ row_ptr, int* __restrict__ col, int E, int n) {
    __shared__ unsigned stmp[BCAP];
    __shared__ int lb[512];
    __shared__ int lo[512];
    __shared__ int sm[256];
    int bk = blockIdx.x;
    int tid = threadIdx.x;
    BSUM_SCAN(sm, bsum, nbK, tid)
    int i0 = bk * EB;
    int c0 = (i0 >> 10), p0 = (c0 == 0) ? 0 : sm[c0 - 1];
    int gbase = ghBM[(size_t)i0] + p0;
    int gend = E;
    if (bk < 255) {
        int i1 = (bk + 1) * EB;
        int c1 = (i1 >> 10), p1 = (c1 == 0) ? 0 : sm[c1 - 1];
        gend = ghBM[(size_t)i1] + p1;
    }
    int cnt = gend - gbase;
    bool lds = (cnt <= BCAP);
    __syncthreads();      // sm reuse barrier before lb init below
    lb[tid] = 0; lb[tid + 256] = 0;
    if (lds) {
        for (int i = tid; i < cnt; i += 256) stmp[i] = tmp[gbase + i];
    }
    __syncthreads();
    if (lds) {
        for (int i = tid; i < cnt; i += 256)
            atomicAdd(&lb[stmp[i] >> 17], 1);
    } else {
        for (int i = tid; i < cnt; i += 256)
            atomicAdd(&lb[tmp[gbase + i] >> 17], 1);
    }
    __syncthreads();
    int p = lb[2 * tid], q = lb[2 * tid + 1];
    int ps = p + q;
    sm[tid] = ps;
    __syncthreads();
    for (int off = 1; off < 256; off <<= 1) {
        int t = (tid >= off) ? sm[tid - off] : 0;
        __syncthreads();
        sm[tid] += t;
        __syncthreads();
    }
    int excl = sm[tid] - ps;
    int e0 = excl, e1 = excl + p;
    lo[2 * tid] = e0; lo[2 * tid + 1] = e1;
    int v0 = bk * 512 + 2 * tid;
    if (v0 <= n) row_ptr[v0] = gbase + e0;
    if (v0 + 1 <= n) row_ptr[v0 + 1] = gbase + e1;
    __syncthreads();
    if (lds) {
        for (int i = tid; i < cnt; i += 256) {
            unsigned v = stmp[i];
            int r = atomicAdd(&lo[v >> 17], 1);
            col[gbase + r] = (int)(v & 0x1FFFFu);
        }
    } else {
        for (int i = tid; i < cnt; i += 256) {
            unsigned v = tmp[gbase + i];
            int r = atomicAdd(&lo[v >> 17], 1);
            col[gbase + r] = (int)(v & 0x1FFFFu);
        }
    }
}

// ---------------------------------------------------------------------------
// Layer2 GEMM via MFMA bf16: [N,128(bf16-packed)]x[128,64].
__global__ __launch_bounds__(256) void gemm2_kernel(
        const unsigned* __restrict__ xp, const float* __restrict__ W,
        const float* __restrict__ att_s, const float* __restrict__ att_d,
        unsigned* __restrict__ hp, float* __restrict__ as_, float* __restrict__ ad_, int n) {
    __shared__ uint4 WtS[1024];                 // 16 KB: Wt[64ch][128k] bf16
    unsigned* Wt = (unsigned*)WtS;
    int tid = threadIdx.x;
    {   // stage W2^T
        int ch = tid & 63, fb = tid >> 6;
        #pragma unroll
        for (int j8 = 0; j8 < 4; ++j8) {
            int f0 = fb * 32 + j8 * 8;
            unsigned pk[4];
            #pragma unroll
            for (int p = 0; p < 4; ++p) {
                float lo = W[(size_t)(f0 + 2 * p) * 64 + ch];
                float hi = W[(size_t)(f0 + 2 * p + 1) * 64 + ch];
                pk[p] = f2bf(lo) | (f2bf(hi) << 16);
            }
            int bcol = (f0 * 2) ^ ((ch & 7) << 4);
            *(uint4*)&Wt[ch * 64 + (bcol >> 2)] = *(uint4*)pk;
        }
    }
    __syncthreads();
    int lane = tid & 63, w = tid >> 6;
    int col = lane & 15, quad = lane >> 4;
    int nodebase = blockIdx.x * 128 + w * 32;
    bf16x8 a[2][4];
    #pragma unroll
    for (int s = 0; s < 2; ++s) {
        int node = nodebase + s * 16 + col;
        bool v = node < n;
        #pragma unroll
        for (int kk = 0; kk < 4; ++kk) {
            uint4 u = v ? *(const uint4*)&xp[(size_t)node * 64 + kk * 16 + quad * 4]
                        : make_uint4(0, 0, 0, 0);
            a[s][kk] = *(bf16x8*)&u;
        }
    }
    f32x4 acc[2][4] = {};
    #pragma unroll
    for (int c = 0; c < 4; ++c) {
        int brow = c * 16 + col;
        bf16x8 b[4];
        #pragma unroll
        for (int kk = 0; kk < 4; ++kk) {
            int bcol = (kk * 64 + quad * 16) ^ ((brow & 7) << 4);
            b[kk] = *(bf16x8*)&Wt[brow * 64 + (bcol >> 2)];
        }
        #pragma unroll
        for (int s = 0; s < 2; ++s)
            #pragma unroll
            for (int kk = 0; kk < 4; ++kk)
                acc[s][c] = __builtin_amdgcn_mfma_f32_16x16x32_bf16(a[s][kk], b[kk], acc[s][c], 0, 0, 0);
    }
    float aS[4], aD[4];
    #pragma unroll
    for (int c = 0; c < 4; ++c) { aS[c] = att_s[c * 16 + col]; aD[c] = att_d[c * 16 + col]; }
    #pragma unroll
    for (int s = 0; s < 2; ++s) {
        #pragma unroll
        for (int c = 0; c < 4; ++c) {
            #pragma unroll
            for (int r = 0; r < 4; ++r) {
                float own = acc[s][c][r];
                float par = SWZ_F(own, 0x041F);
                int node = nodebase + s * 16 + quad * 4 + r;
                if (!(lane & 1) && node < n)
                    hp[(size_t)node * 32 + c * 8 + (col >> 1)] =
                        f2bf(own) | (f2bf(par) << 16);
            }
        }
        #pragma unroll
        for (int r = 0; r < 4; ++r) {
            float ps = 0.f, pd = 0.f;
            #pragma unroll
            for (int c = 0; c < 4; ++c) {
                ps = fmaf(acc[s][c][r], aS[c], ps);
                pd = fmaf(acc[s][c][r], aD[c], pd);
            }
            ps += SWZ_F(ps, 0x041F); pd += SWZ_F(pd, 0x041F);
            ps += SWZ_F(ps, 0x081F); pd += SWZ_F(pd, 0x081F);
            ps += SWZ_F(ps, 0x101F); pd += SWZ_F(pd, 0x101F);
            ps += SWZ_F(ps, 0x201F); pd += SWZ_F(pd, 0x201F);
            int node = nodebase + s * 16 + quad * 4 + r;
            if (col == 0 && node < n) { as_[node] = ps; ad_[node] = pd; }
        }
    }
}

// ---------------------------------------------------------------------------
// Aggregation layer1: wave per dst node, lane owns channels (2l, 2l+1).
#define A1_G8(B, K0) { \
    int t0 = SWZ_I(myc, (((B)+(K0)+0)<<5)); \
    int t1 = SWZ_I(myc, (((B)+(K0)+1)<<5)); \
    int t2 = SWZ_I(myc, (((B)+(K0)+2)<<5)); \
    int t3 = SWZ_I(myc, (((B)+(K0)+3)<<5)); \
    int t4 = SWZ_I(myc, (((B)+(K0)+4)<<5)); \
    int t5 = SWZ_I(myc, (((B)+(K0)+5)<<5)); \
    int t6 = SWZ_I(myc, (((B)+(K0)+6)<<5)); \
    int t7 = SWZ_I(myc, (((B)+(K0)+7)<<5)); \
    unsigned v0 = hp[(size_t)t0 * 64 + lane]; \
    unsigned v1 = hp[(size_t)t1 * 64 + lane]; \
    unsigned v2 = hp[(size_t)t2 * 64 + lane]; \
    unsigned v3 = hp[(size_t)t3 * 64 + lane]; \
    unsigned v4 = hp[(size_t)t4 * 64 + lane]; \
    unsigned v5 = hp[(size_t)t5 * 64 + lane]; \
    unsigned v6 = hp[(size_t)t6 * 64 + lane]; \
    unsigned v7 = hp[(size_t)t7 * 64 + lane]; \
    float q0 = SWZ_F(ew, ((((K0)+0)<<5)|0x10)); \
    float q1 = SWZ_F(ew, ((((K0)+1)<<5)|0x10)); \
    float q2 = SWZ_F(ew, ((((K0)+2)<<5)|0x10)); \
    float q3 = SWZ_F(ew, ((((K0)+3)<<5)|0x10)); \
    float q4 = SWZ_F(ew, ((((K0)+4)<<5)|0x10)); \
    float q5 = SWZ_F(ew, ((((K0)+5)<<5)|0x10)); \
    float q6 = SWZ_F(ew, ((((K0)+6)<<5)|0x10)); \
    float q7 = SWZ_F(ew, ((((K0)+7)<<5)|0x10)); \
    s += q0; acc0 = fmaf(q0, bflo(v0), acc0); acc1 = fmaf(q0, bfhi(v0), acc1); \
    s += q1; acc0 = fmaf(q1, bflo(v1), acc0); acc1 = fmaf(q1, bfhi(v1), acc1); \
    s += q2; acc0 = fmaf(q2, bflo(v2), acc0); acc1 = fmaf(q2, bfhi(v2), acc1); \
    s += q3; acc0 = fmaf(q3, bflo(v3), acc0); acc1 = fmaf(q3, bfhi(v3), acc1); \
    s += q4; acc0 = fmaf(q4, bflo(v4), acc0); acc1 = fmaf(q4, bfhi(v4), acc1); \
    s += q5; acc0 = fmaf(q5, bflo(v5), acc0); acc1 = fmaf(q5, bfhi(v5), acc1); \
    s += q6; acc0 = fmaf(q6, bflo(v6), acc0); acc1 = fmaf(q6, bfhi(v6), acc1); \
    s += q7; acc0 = fmaf(q7, bflo(v7), acc0); acc1 = fmaf(q7, bfhi(v7), acc1); }

#define A1_SUB(B) { \
    int sspec = SWZ_I(myc, (((B)<<5) | 0x0F)); \
    float ee_ = as_[(size_t)sspec * 4 + head] + adv; \
    ee_ = fmaxf(ee_, 0.2f * ee_); \
    float ew = ((cb + (B) + (lane & 15)) < end) ? __expf(ee_) : 0.f; \
    A1_G8(B, 0) \
    if (m > (B) + 8) A1_G8(B, 8) }

__global__ __launch_bounds__(256) void agg1_kernel(
        const unsigned* __restrict__ hp, const float* __restrict__ as_,
        const float* __restrict__ ad_, const int* __restrict__ row_ptr,
        const int* __restrict__ col, const float* __restrict__ bias,
        unsigned* __restrict__ outp, int n) {
    int wid = (blockIdx.x * 256 + threadIdx.x) >> 6;
    int lane = threadIdx.x & 63;
    if (wid >= n) return;
    int node = wid;
    int head = lane >> 4;
    float adv = ad_[(size_t)node * 4 + head];
    float e0 = as_[(size_t)node * 4 + head] + adv;
    e0 = fmaxf(e0, 0.2f * e0);
    float w0 = __expf(e0);
    float s = w0;
    unsigned u0 = hp[(size_t)node * 64 + lane];
    float acc0 = w0 * bflo(u0), acc1 = w0 * bfhi(u0);
    int beg = row_ptr[node], end = row_ptr[node + 1];
    for (int cb = beg; cb < end; cb += 32) {
        int m = end - cb; if (m > 32) m = 32;
        int ci = cb + (lane & 31);
        int myc = col[(ci < end) ? ci : (end - 1)];
        A1_SUB(0)
        if (m > 16) A1_SUB(16)
    }
    float inv = 1.0f / (s + 1e-16f);
    float2 b = *(const float2*)&bias[lane * 2];
    outp[(size_t)node * 64 + lane] =
        f2bf(acc0 * inv + b.x) | (f2bf(acc1 * inv + b.y) << 16);
}

// Aggregation layer2: wave per dst node; halves process even/odd edges.
#define A2_G4(K0) { \
    int t0 = SWZ_I(myc, (((K0)+0)<<5)); \
    int t1 = SWZ_I(myc, (((K0)+1)<<5)); \
    int t2 = SWZ_I(myc, (((K0)+2)<<5)); \
    int t3 = SWZ_I(myc, (((K0)+3)<<5)); \
    unsigned v0 = hp[(size_t)t0 * 32 + wrd]; \
    unsigned v1 = hp[(size_t)t1 * 32 + wrd]; \
    unsigned v2 = hp[(size_t)t2 * 32 + wrd]; \
    unsigned v3 = hp[(size_t)t3 * 32 + wrd]; \
    float q0 = SWZ_F(ew, (((K0)+0)<<5)); \
    float q1 = SWZ_F(ew, (((K0)+1)<<5)); \
    float q2 = SWZ_F(ew, (((K0)+2)<<5)); \
    float q3 = SWZ_F(ew, (((K0)+3)<<5)); \
    s += q0; acc0 = fmaf(q0, bflo(v0), acc0); acc1 = fmaf(q0, bfhi(v0), acc1); \
    s += q1; acc0 = fmaf(q1, bflo(v1), acc0); acc1 = fmaf(q1, bfhi(v1), acc1); \
    s += q2; acc0 = fmaf(q2, bflo(v2), acc0); acc1 = fmaf(q2, bfhi(v2), acc1); \
    s += q3; acc0 = fmaf(q3, bflo(v3), acc0); acc1 = fmaf(q3, bfhi(v3), acc1); }

__global__ __launch_bounds__(256) void agg2_kernel(
        const unsigned* __restrict__ hp, const float* __restrict__ as_,
        const float* __restrict__ ad_, const int* __restrict__ row_ptr,
        const int* __restrict__ col, const float* __restrict__ bias,
        float* __restrict__ out, int n) {
    int wid = (blockIdx.x * 256 + threadIdx.x) >> 6;
    int lane = threadIdx.x & 63;
    if (wid >= n) return;
    int node = wid;
    int half = lane >> 5, wrd = lane & 31;
    float adv = ad_[node];
    float s = 0.f, acc0 = 0.f, acc1 = 0.f;
    {
        float e = as_[node] + adv; e = fmaxf(e, 0.2f * e);
        float w = __expf(e);
        if (half == 0) {
            unsigned u = hp[(size_t)node * 32 + wrd];
            s = w; acc0 = w * bflo(u); acc1 = w * bfhi(u);
        }
    }
    int beg = row_ptr[node], end = row_ptr[node + 1];
    for (int cb = beg; cb < end; cb += 64) {
        int m = end - cb; if (m > 64) m = 64;
        int idx = cb + 2 * (lane & 31) + half;
        int myc = col[(idx < end) ? idx : (end - 1)];
        float ee = as_[myc] + adv; ee = fmaxf(ee, 0.2f * ee);
        float ew = (idx < end) ? __expf(ee) : 0.f;
        A2_G4(0)
        if (m > 8)  A2_G4(4)
        if (m > 16) A2_G4(8)
        if (m > 24) A2_G4(12)
        if (m > 32) {
            A2_G4(16)
            if (m > 40) A2_G4(20)
            if (m > 48) A2_G4(24)
            if (m > 56) A2_G4(28)
        }
    }
    s += __shfl_xor(s, 32);
    acc0 += __shfl_xor(acc0, 32);
    acc1 += __shfl_xor(acc1, 32);
    if (half == 0) {
        float inv = 1.0f / (s + 1e-16f);
        float2 b = *(const float2*)&bias[wrd * 2];
        *(float2*)&out[(size_t)node * 64 + wrd * 2] =
            make_float2(acc0 * inv + b.x, acc1 * inv + b.y);
    }
}

// ---------------------------------------------------------------------------
extern "C" void kernel_launch(void* const* d_in, const int* in_sizes, int n_in,
                              void* d_out, int out_size, void* d_ws, size_t ws_size,
                              hipStream_t stream) {
    const float* inp   = (const float*)d_in[0];
    const int*   ei    = (const int*)d_in[1];
    const float* W1    = (const float*)d_in[2];
    const float* atts1 = (const float*)d_in[3];
    const float* attd1 = (const float*)d_in[4];
    const float* bias1 = (const float*)d_in[5];
    const float* W2    = (const float*)d_in[6];
    const float* atts2 = (const float*)d_in[7];
    const float* attd2 = (const float*)d_in[8];
    const float* bias2 = (const float*)d_in[9];
    float* out = (float*)d_out;

    const int N = N_NODES;
    const int E = in_sizes[1] / 2;

    const int EB = (E + 2047) / 2048;          // edge blocks
    const int K = 256 * EB;                    // ghBM length
    const int nbK = (K + SCAN_BLOCK - 1) / SCAN_BLOCK;   // <=256 for E<=2M
    const int nG1 = (N + 127) / 128;           // gemm1 blocks

    unsigned* h1p = (unsigned*)d_ws;               // N*64 uints (layer2 reuses N*32)
    unsigned* x1p = h1p + (size_t)N * 64;          // N*64 uints (bf16-packed x1)
    float* as1 = (float*)(x1p + (size_t)N * 64);   // N*4
    float* ad1 = as1 + (size_t)N * 4;              // N*4
    int* row_ptr  = (int*)(ad1 + (size_t)N * 4);   // N+1
    int* col      = row_ptr + N + 1;               // E
    int* ghBM     = col + E;                       // 256*EB
    int* bsum     = ghBM + K;                      // 256
    unsigned* tmp = x1p;                           // E uints, aliases x1p (dead until agg1)

    // CSR build (hist fused with layer1 GEMM; scan finalized in consumers)
    histgemm1_kernel<<<EB + nG1, 256, 0, stream>>>(
        ei, ghBM, EB, E, inp, W1, atts1, attd1, h1p, as1, ad1, N);
    pscanA_kernel<<<nbK, SCAN_BLOCK, 0, stream>>>(ghBM, bsum, K);
    scatterB_kernel<<<EB, 256, 0, stream>>>(ei, ghBM, EB, bsum, nbK, tmp, E);
    bucketC_kernel<<<256, 256, 0, stream>>>(tmp, ghBM, EB, bsum, nbK, row_ptr, col, E, N);

    agg1_kernel<<<(N + 3) / 4, 256, 0, stream>>>(h1p, as1, ad1, row_ptr, col, bias1, x1p, N);

    // layer 2 (h2p aliases h1p; as2/ad2 alias as1/ad1)
    gemm2_kernel<<<(N + 127) / 128, 256, 0, stream>>>(x1p, W2, atts2, attd2, h1p, as1, ad1, N);
    agg2_kernel<<<(N + 3) / 4, 256, 0, stream>>>(h1p, as1, ad1, row_ptr, col, bias2, out, N);
}